// Round 14
// baseline (2523.120 us; speedup 1.0000x reference)
//
#include <hip/hip_runtime.h>
#include <hip/hip_bf16.h>

#define BATCH 2048
#define LSIG 2048
#define TSTEPS 512
#define CH 16
#define NCHUNK (TSTEPS / CH)

typedef float v2f __attribute__((ext_vector_type(2)));
typedef float v4f __attribute__((ext_vector_type(4)));
typedef __bf16 b16x8 __attribute__((ext_vector_type(8)));
typedef float f32x4 __attribute__((ext_vector_type(4)));

#define PKFMA(d, a, b) asm("v_pk_fma_f32 %0, %1, %2, %0" : "+v"(d) : "v"(a), "v"(b))

__device__ __forceinline__ float sigf(float x) {
    return __fdividef(1.f, 1.f + __expf(-x));
}
__device__ __forceinline__ float tanhfast(float x) {
    return 1.f - __fdividef(2.f, __expf(2.f * x) + 1.f);
}
__device__ __forceinline__ unsigned short bf16rne(float f) {
    unsigned u = __float_as_uint(f);
    return (unsigned short)((u + 0x7FFFu + ((u >> 16) & 1u)) >> 16);
}
__device__ __forceinline__ int swz(int co) {
    return (co < 16) ? ((co >> 2) * 8 + (co & 3))
                     : (((co >> 2) - 4) * 8 + 4 + (co & 3));
}

// ============ K1: conv front-end for ONE chunk -> seq hi/lo planes =========
__global__ __launch_bounds__(64) void frontend_kernel(
    const float* __restrict__ x0, const float* __restrict__ x1,
    const float* __restrict__ x2, const float* __restrict__ x3,
    const float* __restrict__ c1w, const float* __restrict__ c1b,
    const float* __restrict__ c2w, const float* __restrict__ c2b,
    unsigned short* __restrict__ seqh, unsigned short* __restrict__ seql,
    int t0, int Tseg)
{
    const int s    = blockIdx.x;
    const int br   = blockIdx.y & 3;
    const int ck   = blockIdx.y >> 2;
    const int lane = threadIdx.x;
    const float* xg = (br == 0) ? x0 : (br == 1) ? x1 : (br == 2) ? x2 : x3;

    __shared__ float xs_c[70];
    __shared__ float p1buf[34][16];

    const int ci = lane & 15;
    const int co = lane & 31;
    const int hf = lane >> 5;
    const int sp = swz(co);
    const int tc0 = t0 + ck * CH;
    const int lt0 = ck * CH;

    const float w10 = c1w[br * 48 + ci * 3 + 0];
    const float w11 = c1w[br * 48 + ci * 3 + 1];
    const float w12 = c1w[br * 48 + ci * 3 + 2];
    const float b1v = c1b[br * 16 + ci];

    float wt[24];
    {
        const v4f* p = (const v4f*)(c2w + br * 1536 + co * 48 + hf * 24);
        #pragma unroll
        for (int i = 0; i < 6; ++i) ((v4f*)wt)[i] = p[i];
    }
    v4f w2p[3][2];
    #pragma unroll
    for (int k = 0; k < 3; ++k)
        #pragma unroll
        for (int h2 = 0; h2 < 2; ++h2)
            w2p[k][h2] = (v4f){ wt[(h2 * 4 + 0) * 3 + k], wt[(h2 * 4 + 1) * 3 + k],
                                wt[(h2 * 4 + 2) * 3 + k], wt[(h2 * 4 + 3) * 3 + k] };
    const float b2v = c2b[br * 32 + co];

    {
        int g = 4 * tc0 - 3 + lane;
        xs_c[lane] = ((unsigned)g < (unsigned)LSIG) ? xg[(size_t)s * LSIG + g] : 0.f;
        if (lane < 6) {
            int g2 = 4 * tc0 + 61 + lane;
            xs_c[64 + lane] = ((unsigned)g2 < (unsigned)LSIG) ? xg[(size_t)s * LSIG + g2] : 0.f;
        }
    }
    __syncthreads();

    #pragma unroll 1
    for (int it = 0; it < 9; ++it) {
        int idx = it * 64 + lane;
        if (idx < 34 * 16) {
            int pl = idx >> 4;
            float xa = xs_c[2 * pl + 0], xb = xs_c[2 * pl + 1];
            float xc = xs_c[2 * pl + 2], xd = xs_c[2 * pl + 3];
            float a0 = fmaf(xc, w12, fmaf(xb, w11, fmaf(xa, w10, b1v)));
            float a1 = fmaf(xd, w12, fmaf(xc, w11, fmaf(xb, w10, b1v)));
            float v = fmaxf(fmaxf(a0, a1), 0.f);
            int p1g = 2 * tc0 - 1 + pl;
            v = ((unsigned)p1g < (unsigned)(LSIG / 2)) ? v : 0.f;
            p1buf[pl][idx & 15] = v;
        }
    }
    __syncthreads();

    {
        const v4f* pbase = (const v4f*)&p1buf[0][0];
        const int h2o = hf * 2;
        v4f r0a = pbase[0 * 4 + h2o], r0b = pbase[0 * 4 + h2o + 1];
        v4f r1a = pbase[1 * 4 + h2o], r1b = pbase[1 * 4 + h2o + 1];
        v4f r2a = pbase[2 * 4 + h2o], r2b = pbase[2 * 4 + h2o + 1];
        v4f r3a = pbase[3 * 4 + h2o], r3b = pbase[3 * 4 + h2o + 1];
        #pragma unroll 1
        for (int tl = 0; tl < CH; ++tl) {
            v2f aA = {0.f, 0.f}, aB = {0.f, 0.f};
            PKFMA(aA, r0a.xy, w2p[0][0].xy); PKFMA(aA, r0a.zw, w2p[0][0].zw);
            PKFMA(aA, r0b.xy, w2p[0][1].xy); PKFMA(aA, r0b.zw, w2p[0][1].zw);
            PKFMA(aA, r1a.xy, w2p[1][0].xy); PKFMA(aA, r1a.zw, w2p[1][0].zw);
            PKFMA(aA, r1b.xy, w2p[1][1].xy); PKFMA(aA, r1b.zw, w2p[1][1].zw);
            PKFMA(aA, r2a.xy, w2p[2][0].xy); PKFMA(aA, r2a.zw, w2p[2][0].zw);
            PKFMA(aA, r2b.xy, w2p[2][1].xy); PKFMA(aA, r2b.zw, w2p[2][1].zw);
            PKFMA(aB, r1a.xy, w2p[0][0].xy); PKFMA(aB, r1a.zw, w2p[0][0].zw);
            PKFMA(aB, r1b.xy, w2p[0][1].xy); PKFMA(aB, r1b.zw, w2p[0][1].zw);
            PKFMA(aB, r2a.xy, w2p[1][0].xy); PKFMA(aB, r2a.zw, w2p[1][0].zw);
            PKFMA(aB, r2b.xy, w2p[1][1].xy); PKFMA(aB, r2b.zw, w2p[1][1].zw);
            PKFMA(aB, r3a.xy, w2p[2][0].xy); PKFMA(aB, r3a.zw, w2p[2][0].zw);
            PKFMA(aB, r3b.xy, w2p[2][1].xy); PKFMA(aB, r3b.zw, w2p[2][1].zw);
            float sA = aA.x + aA.y, sB = aB.x + aB.y;
            sA += __shfl_xor(sA, 32);
            sB += __shfl_xor(sB, 32);
            float sv = fmaxf(fmaxf(sA, sB) + b2v, 0.f);
            unsigned short hb = bf16rne(sv);
            float hif = __uint_as_float(((unsigned)hb) << 16);
            unsigned short lb = bf16rne(sv - hif);
            size_t off = (((size_t)br * Tseg + (lt0 + tl)) * 2048 + s) * 32 + sp;
            if (hf == 0) seqh[off] = hb;
            else         seql[off] = lb;
            r0a = r2a; r0b = r2b; r1a = r3a; r1b = r3b;
            if (tl < CH - 1) {
                r2a = pbase[(2 * tl + 4) * 4 + h2o]; r2b = pbase[(2 * tl + 4) * 4 + h2o + 1];
                r3a = pbase[(2 * tl + 5) * 4 + h2o]; r3b = pbase[(2 * tl + 5) * 4 + h2o + 1];
            }
        }
    }
}

// ============ K2: MFMA LSTM, TWO 16-sample streams per wave ================
// D layout (verified R12): col=lane&15 (sample), row=4q+r -> each lane holds
// i,f,g,o of units {4q+r,16+4q+r}; that IS the next step's B-frag.
// Stream interleave: accA=chains(x0,h0) || advance(stream1<-accB);
//                    accB=chains(x1,h1') || advance(stream0<-accA).
// In-wave ILP fills the ~60% per-step stall R12 measured (1 wave/SIMD).
#define GATE_CHAINS(ACC, XH, XL, HH, HL)                                        \
    {                                                                           \
        _Pragma("unroll")                                                       \
        for (int n = 0; n < 8; ++n) {                                           \
            f32x4 a_ = bias_lds[n][lane];                                       \
            a_ = __builtin_amdgcn_mfma_f32_16x16x32_bf16(wihhi[n], XH, a_, 0, 0, 0); \
            a_ = __builtin_amdgcn_mfma_f32_16x16x32_bf16(wihhi[n], XL, a_, 0, 0, 0); \
            a_ = __builtin_amdgcn_mfma_f32_16x16x32_bf16(wihlo[n], XH, a_, 0, 0, 0); \
            a_ = __builtin_amdgcn_mfma_f32_16x16x32_bf16(whhhi[n], HH, a_, 0, 0, 0); \
            a_ = __builtin_amdgcn_mfma_f32_16x16x32_bf16(whhhi[n], HL, a_, 0, 0, 0); \
            a_ = __builtin_amdgcn_mfma_f32_16x16x32_bf16(whhlo[n], HH, a_, 0, 0, 0); \
            ACC[n] = a_;                                                        \
        }                                                                       \
    }

#define ADVANCE(ACC, HH, HL, CS, LAST, FP)                                      \
    {                                                                           \
        _Pragma("unroll")                                                       \
        for (int h2_ = 0; h2_ < 2; ++h2_) {                                     \
            _Pragma("unroll")                                                   \
            for (int r_ = 0; r_ < 4; ++r_) {                                    \
                float gi = ACC[0 + h2_][r_];                                    \
                float gf = ACC[2 + h2_][r_];                                    \
                float gg = ACC[4 + h2_][r_];                                    \
                float go = ACC[6 + h2_][r_];                                    \
                float si = sigf(gi), sf = sigf(gf);                             \
                float tg = tanhfast(gg), so = sigf(go);                         \
                float cc = fmaf(sf, CS[h2_][r_], si * tg);                      \
                CS[h2_][r_] = cc;                                               \
                float hv = so * tanhfast(cc);                                   \
                __bf16 hb2 = (__bf16)hv;                                        \
                HH[h2_ * 4 + r_] = hb2;                                         \
                HL[h2_ * 4 + r_] = (__bf16)(hv - (float)hb2);                   \
                if (LAST) FP[16 * h2_ + 4 * q + r_] = hv;                       \
            }                                                                   \
        }                                                                       \
    }

__global__ __launch_bounds__(64, 1) void lstm_mfma_kernel(
    const unsigned short* __restrict__ seqh, const unsigned short* __restrict__ seql,
    const float* __restrict__ wih, const float* __restrict__ whh,
    const float* __restrict__ bih, const float* __restrict__ bhh,
    float* __restrict__ state, float* __restrict__ feats,
    int t0, int Tseg)
{
    const int g0   = blockIdx.x * 32;   // stream0: g0.., stream1: g0+16..
    const int br   = blockIdx.y;
    const int lane = threadIdx.x;
    const int c    = lane & 15;
    const int q    = lane >> 4;

    __shared__ f32x4 bias_lds[8][64];
    #pragma unroll
    for (int n = 0; n < 8; ++n) {
        f32x4 b;
        #pragma unroll
        for (int r = 0; r < 4; ++r) {
            int g = 16 * n + 4 * q + r;
            b[r] = bih[br * 128 + g] + bhh[br * 128 + g];
        }
        bias_lds[n][lane] = b;
    }
    __syncthreads();

    // weight A-frags: row = c (gate 16n+c), k elems {4q+j} u {16+4q+j}
    b16x8 wihhi[8], wihlo[8], whhhi[8], whhlo[8];
    #pragma unroll
    for (int n = 0; n < 8; ++n) {
        const int gr = 16 * n + c;
        const float* pi = wih + (size_t)br * 4096 + (size_t)gr * 32;
        const float* ph = whh + (size_t)br * 4096 + (size_t)gr * 32;
        v4f ia = *(const v4f*)(pi + 4 * q);
        v4f ib = *(const v4f*)(pi + 16 + 4 * q);
        v4f ha = *(const v4f*)(ph + 4 * q);
        v4f hb = *(const v4f*)(ph + 16 + 4 * q);
        #pragma unroll
        for (int j = 0; j < 4; ++j) {
            __bf16 tt;
            tt = (__bf16)ia[j]; wihhi[n][j]     = tt; wihlo[n][j]     = (__bf16)(ia[j] - (float)tt);
            tt = (__bf16)ib[j]; wihhi[n][4 + j] = tt; wihlo[n][4 + j] = (__bf16)(ib[j] - (float)tt);
            tt = (__bf16)ha[j]; whhhi[n][j]     = tt; whhlo[n][j]     = (__bf16)(ha[j] - (float)tt);
            tt = (__bf16)hb[j]; whhhi[n][4 + j] = tt; whhlo[n][4 + j] = (__bf16)(hb[j] - (float)tt);
        }
    }

    // per-stream state
    b16x8 h0h, h0l, h1h, h1l;
    float cs0[2][4], cs1[2][4];
    if (t0 == 0) {
        #pragma unroll
        for (int j = 0; j < 8; ++j) {
            h0h[j] = (__bf16)0.f; h0l[j] = (__bf16)0.f;
            h1h[j] = (__bf16)0.f; h1l[j] = (__bf16)0.f;
        }
        #pragma unroll
        for (int h2 = 0; h2 < 2; ++h2)
            #pragma unroll
            for (int r = 0; r < 4; ++r) { cs0[h2][r] = 0.f; cs1[h2][r] = 0.f; }
    } else {
        const float* st0 = state + (((size_t)br * BATCH + g0 + c) * 2) * 32;
        const float* st1 = state + (((size_t)br * BATCH + g0 + 16 + c) * 2) * 32;
        #pragma unroll
        for (int h2 = 0; h2 < 2; ++h2)
            #pragma unroll
            for (int r = 0; r < 4; ++r) {
                int u = 16 * h2 + 4 * q + r;
                float hv0 = st0[u], hv1 = st1[u];
                __bf16 b0 = (__bf16)hv0, b1 = (__bf16)hv1;
                h0h[h2 * 4 + r] = b0; h0l[h2 * 4 + r] = (__bf16)(hv0 - (float)b0);
                h1h[h2 * 4 + r] = b1; h1l[h2 * 4 + r] = (__bf16)(hv1 - (float)b1);
                cs0[h2][r] = st0[32 + u];
                cs1[h2][r] = st1[32 + u];
            }
    }

    float* fp0 = feats + ((size_t)br * BATCH + g0 + c) * 32;
    float* fp1 = feats + ((size_t)br * BATCH + g0 + 16 + c) * 32;

    // x offsets
    const size_t xbase0 = ((size_t)br * Tseg * 2048 + g0 + c) * 32 + (size_t)q * 8;
    const size_t xbase1 = xbase0 + 16 * 32;
    const size_t xstep  = 2048 * 32;

    // prologue: x0(0), x1(0); accB = stream1 gates(step 0)
    b16x8 x0h = *(const b16x8*)(seqh + xbase0);
    b16x8 x0l = *(const b16x8*)(seql + xbase0);
    f32x4 accA[8], accB[8];
    {
        b16x8 p1h = *(const b16x8*)(seqh + xbase1);
        b16x8 p1l = *(const b16x8*)(seql + xbase1);
        GATE_CHAINS(accB, p1h, p1l, h1h, h1l);
    }

    #pragma unroll 1
    for (int t = 0; t < Tseg; ++t) {
        const bool more = (t < Tseg - 1);
        const bool last = (t0 + t == TSTEPS - 1);
        b16x8 n0h, n0l, n1h, n1l;
        if (more) {
            size_t r0 = xbase0 + (size_t)(t + 1) * xstep;
            size_t r1 = xbase1 + (size_t)(t + 1) * xstep;
            n0h = *(const b16x8*)(seqh + r0); n0l = *(const b16x8*)(seql + r0);
            n1h = *(const b16x8*)(seqh + r1); n1l = *(const b16x8*)(seql + r1);
        }

        // stream0 MFMAs (overlap with stream1 VALU below)
        GATE_CHAINS(accA, x0h, x0l, h0h, h0l);
        // stream1 advance step t (consumes accB)
        ADVANCE(accB, h1h, h1l, cs1, last, fp1);
        // stream1 MFMAs for step t+1 (overlap with stream0 VALU below)
        if (more) { GATE_CHAINS(accB, n1h, n1l, h1h, h1l); }
        // stream0 advance step t (consumes accA)
        ADVANCE(accA, h0h, h0l, cs0, last, fp0);

        x0h = n0h; x0l = n0l;
    }

    // save state for next segment
    if (t0 + Tseg < TSTEPS) {
        float* st0 = state + (((size_t)br * BATCH + g0 + c) * 2) * 32;
        float* st1 = state + (((size_t)br * BATCH + g0 + 16 + c) * 2) * 32;
        #pragma unroll
        for (int h2 = 0; h2 < 2; ++h2)
            #pragma unroll
            for (int r = 0; r < 4; ++r) {
                int u = 16 * h2 + 4 * q + r;
                st0[u]      = (float)h0h[h2 * 4 + r] + (float)h0l[h2 * 4 + r];
                st0[32 + u] = cs0[h2][r];
                st1[u]      = (float)h1h[h2 * 4 + r] + (float)h1l[h2 * 4 + r];
                st1[32 + u] = cs1[h2][r];
            }
    }
}

// ============ fallback: R7 monolithic branch kernel ========================
__global__ __launch_bounds__(64, 2) void branch_fallback(
    const float* __restrict__ x0, const float* __restrict__ x1,
    const float* __restrict__ x2, const float* __restrict__ x3,
    const float* __restrict__ c1w, const float* __restrict__ c1b,
    const float* __restrict__ c2w, const float* __restrict__ c2b,
    const float* __restrict__ wih, const float* __restrict__ whh,
    const float* __restrict__ bih, const float* __restrict__ bhh,
    float* __restrict__ feats)
{
    const int s    = blockIdx.x;
    const int br   = blockIdx.y;
    const int lane = threadIdx.x;
    const float* xg = (br == 0) ? x0 : (br == 1) ? x1 : (br == 2) ? x2 : x3;

    __shared__ float xs_c[70];
    __shared__ float p1buf[34][16];
    __shared__ float seqb[CH][32];
    __shared__ float hb[2][32];

    const int ci = lane & 15;
    const int co = lane & 31;
    const int hf = lane >> 5;

    const float bs0 = bih[br * 128 + lane]      + bhh[br * 128 + lane];
    const float bs1 = bih[br * 128 + lane + 64] + bhh[br * 128 + lane + 64];

    if (lane < 32) hb[0][lane] = 0.f;
    float c_state = 0.f;

    #pragma unroll 1
    for (int chk = 0; chk < NCHUNK; ++chk) {
        const int tc0 = chk * CH;
        {
            int g = 4 * tc0 - 3 + lane;
            xs_c[lane] = ((unsigned)g < (unsigned)LSIG) ? xg[(size_t)s * LSIG + g] : 0.f;
            if (lane < 6) {
                int g2 = 4 * tc0 + 61 + lane;
                xs_c[64 + lane] = ((unsigned)g2 < (unsigned)LSIG) ? xg[(size_t)s * LSIG + g2] : 0.f;
            }
        }
        const float* pc1 = c1w + br * 48 + ci * 3;  asm volatile("" : "+v"(pc1));
        const float w10 = pc1[0], w11 = pc1[1], w12 = pc1[2];
        const float* pb1 = c1b + br * 16 + ci;      asm volatile("" : "+v"(pb1));
        const float b1v = pb1[0];
        const float* pc2 = c2w + br * 1536 + co * 48 + hf * 24;
        asm volatile("" : "+v"(pc2));
        float wt[24];
        #pragma unroll
        for (int i = 0; i < 6; ++i) ((v4f*)wt)[i] = ((const v4f*)pc2)[i];
        v4f w2p[3][2];
        #pragma unroll
        for (int k = 0; k < 3; ++k)
            #pragma unroll
            for (int h2 = 0; h2 < 2; ++h2)
                w2p[k][h2] = (v4f){ wt[(h2 * 4 + 0) * 3 + k], wt[(h2 * 4 + 1) * 3 + k],
                                    wt[(h2 * 4 + 2) * 3 + k], wt[(h2 * 4 + 3) * 3 + k] };
        const float* pb2 = c2b + br * 32 + co;      asm volatile("" : "+v"(pb2));
        const float b2v = pb2[0];
        __syncthreads();
        #pragma unroll 1
        for (int it = 0; it < 9; ++it) {
            int idx = it * 64 + lane;
            if (idx < 34 * 16) {
                int pl = idx >> 4;
                float xa = xs_c[2 * pl + 0], xb = xs_c[2 * pl + 1];
                float xc = xs_c[2 * pl + 2], xd = xs_c[2 * pl + 3];
                float a0 = fmaf(xc, w12, fmaf(xb, w11, fmaf(xa, w10, b1v)));
                float a1 = fmaf(xd, w12, fmaf(xc, w11, fmaf(xb, w10, b1v)));
                float v = fmaxf(fmaxf(a0, a1), 0.f);
                int p1g = 2 * tc0 - 1 + pl;
                v = ((unsigned)p1g < (unsigned)(LSIG / 2)) ? v : 0.f;
                p1buf[pl][idx & 15] = v;
            }
        }
        __syncthreads();
        {
            const v4f* pbase = (const v4f*)&p1buf[0][0];
            const int h2o = hf * 2;
            v4f r0a = pbase[0 * 4 + h2o], r0b = pbase[0 * 4 + h2o + 1];
            v4f r1a = pbase[1 * 4 + h2o], r1b = pbase[1 * 4 + h2o + 1];
            v4f r2a = pbase[2 * 4 + h2o], r2b = pbase[2 * 4 + h2o + 1];
            v4f r3a = pbase[3 * 4 + h2o], r3b = pbase[3 * 4 + h2o + 1];
            #pragma unroll 1
            for (int tl = 0; tl < CH; ++tl) {
                v2f aA = {0.f, 0.f}, aB = {0.f, 0.f};
                PKFMA(aA, r0a.xy, w2p[0][0].xy); PKFMA(aA, r0a.zw, w2p[0][0].zw);
                PKFMA(aA, r0b.xy, w2p[0][1].xy); PKFMA(aA, r0b.zw, w2p[0][1].zw);
                PKFMA(aA, r1a.xy, w2p[1][0].xy); PKFMA(aA, r1a.zw, w2p[1][0].zw);
                PKFMA(aA, r1b.xy, w2p[1][1].xy); PKFMA(aA, r1b.zw, w2p[1][1].zw);
                PKFMA(aA, r2a.xy, w2p[2][0].xy); PKFMA(aA, r2a.zw, w2p[2][0].zw);
                PKFMA(aA, r2b.xy, w2p[2][1].xy); PKFMA(aA, r2b.zw, w2p[2][1].zw);
                PKFMA(aB, r1a.xy, w2p[0][0].xy); PKFMA(aB, r1a.zw, w2p[0][0].zw);
                PKFMA(aB, r1b.xy, w2p[0][1].xy); PKFMA(aB, r1b.zw, w2p[0][1].zw);
                PKFMA(aB, r2a.xy, w2p[1][0].xy); PKFMA(aB, r2a.zw, w2p[1][0].zw);
                PKFMA(aB, r2b.xy, w2p[1][1].xy); PKFMA(aB, r2b.zw, w2p[1][1].zw);
                PKFMA(aB, r3a.xy, w2p[2][0].xy); PKFMA(aB, r3a.zw, w2p[2][0].zw);
                PKFMA(aB, r3b.xy, w2p[2][1].xy); PKFMA(aB, r3b.zw, w2p[2][1].zw);
                float sA = aA.x + aA.y, sB = aB.x + aB.y;
                sA += __shfl_xor(sA, 32);
                sB += __shfl_xor(sB, 32);
                if (hf == 0)
                    seqb[tl][co] = fmaxf(fmaxf(sA, sB) + b2v, 0.f);
                r0a = r2a; r0b = r2b; r1a = r3a; r1b = r3b;
                if (tl < CH - 1) {
                    r2a = pbase[(2 * tl + 4) * 4 + h2o]; r2b = pbase[(2 * tl + 4) * 4 + h2o + 1];
                    r3a = pbase[(2 * tl + 5) * 4 + h2o]; r3b = pbase[(2 * tl + 5) * 4 + h2o + 1];
                }
            }
        }
        __syncthreads();
        float gpx0[CH], gpx1[CH];
        {
            const float* pwi = wih + (size_t)br * 4096 + (size_t)lane * 32;
            asm volatile("" : "+v"(pwi));
            v4f wiA[8], wiB[8];
            #pragma unroll
            for (int j = 0; j < 8; ++j) {
                wiA[j] = ((const v4f*)pwi)[j];
                wiB[j] = ((const v4f*)(pwi + 64 * 32))[j];
            }
            #pragma unroll
            for (int tl = 0; tl < CH; ++tl) {
                const v4f* xq = (const v4f*)&seqb[tl][0];
                v2f aA = {0.f, 0.f}, aB = {0.f, 0.f};
                #pragma unroll
                for (int j = 0; j < 8; ++j) {
                    v4f xv = xq[j];
                    PKFMA(aA, xv.xy, wiA[j].xy); PKFMA(aA, xv.zw, wiA[j].zw);
                    PKFMA(aB, xv.xy, wiB[j].xy); PKFMA(aB, xv.zw, wiB[j].zw);
                }
                gpx0[tl] = aA.x + aA.y;
                gpx1[tl] = aB.x + aB.y;
            }
        }
        {
            const float* pwh = whh + (size_t)br * 4096 + (size_t)lane * 32;
            asm volatile("" : "+v"(pwh));
            v4f whA[8], whB[8];
            #pragma unroll
            for (int j = 0; j < 8; ++j) {
                whA[j] = ((const v4f*)pwh)[j];
                whB[j] = ((const v4f*)(pwh + 64 * 32))[j];
            }
            #pragma unroll
            for (int tl = 0; tl < CH; ++tl) {
                __syncthreads();
                const int p = (tc0 + tl) & 1;
                const v4f* hq = (const v4f*)&hb[p][0];
                v2f aA = {0.f, 0.f}, aB = {0.f, 0.f};
                #pragma unroll
                for (int j = 0; j < 8; ++j) {
                    v4f hv = hq[j];
                    PKFMA(aA, hv.xy, whA[j].xy); PKFMA(aA, hv.zw, whA[j].zw);
                    PKFMA(aB, hv.xy, whB[j].xy); PKFMA(aB, hv.zw, whB[j].zw);
                }
                float g0 = bs0 + gpx0[tl] + aA.x + aA.y;
                float g1 = bs1 + gpx1[tl] + aB.x + aB.y;
                float a0 = sigf(g0);
                float earg = (lane < 32) ? 2.f * g1 : -g1;
                float e1 = __expf(fminf(earg, 80.f));
                float num = (lane < 32) ? e1 - 1.f : 1.f;
                float a1 = __fdividef(num, e1 + 1.f);
                float fa = __shfl_xor(a0, 32);
                float oa = __shfl_xor(a1, 32);
                if (lane < 32) {
                    c_state = fmaf(fa, c_state, a0 * a1);
                    hb[p ^ 1][lane] = oa * tanhfast(c_state);
                }
            }
        }
    }
    __syncthreads();
    if (lane < 32)
        feats[((size_t)br * BATCH + s) * 32 + lane] = hb[0][lane];
}

// ---------------- tail: bottleneck + 8-qubit statevector + classifier -------

__device__ __forceinline__ void apply1q(float2* psi, int lane, int q,
                                        float2 g00, float2 g01,
                                        float2 g10, float2 g11)
{
    const int shift = 7 - q;
    const int right = 1 << shift;
    #pragma unroll
    for (int pp = 0; pp < 2; ++pp) {
        int p  = lane + 64 * pp;
        int l  = p >> shift;
        int r  = p & (right - 1);
        int i0 = (l << (shift + 1)) + r;
        int i1 = i0 + right;
        float2 a = psi[i0], b = psi[i1];
        float2 n0 = make_float2(g00.x * a.x - g00.y * a.y + g01.x * b.x - g01.y * b.y,
                                g00.x * a.y + g00.y * a.x + g01.x * b.y + g01.y * b.x);
        float2 n1 = make_float2(g10.x * a.x - g10.y * a.y + g11.x * b.x - g11.y * b.y,
                                g10.x * a.y + g10.y * a.x + g11.x * b.y + g11.y * b.x);
        psi[i0] = n0;
        psi[i1] = n1;
    }
    __syncthreads();
}

__global__ __launch_bounds__(64) void tail_kernel(
    const float* __restrict__ feats, const float* __restrict__ bw,
    const float* __restrict__ bb, const float* __restrict__ qw,
    const float* __restrict__ cw, const float* __restrict__ cb,
    float* __restrict__ out)
{
    const int s    = blockIdx.x;
    const int lane = threadIdx.x;

    __shared__ float comb[128];
    __shared__ float2 psi[256];
    __shared__ float ang[8];

    comb[lane]      = feats[(size_t)(lane >> 5) * (BATCH * 32) + (size_t)s * 32 + (lane & 31)];
    comb[lane + 64] = feats[(size_t)((lane + 64) >> 5) * (BATCH * 32) + (size_t)s * 32 + (lane & 31)];
    __syncthreads();

    {
        int q = lane >> 3, k0 = lane & 7;
        float p = 0.f;
        #pragma unroll
        for (int i = 0; i < 16; ++i) {
            int k = k0 + 8 * i;
            p = fmaf(comb[k], bw[q * 128 + k], p);
        }
        p += __shfl_xor(p, 4);
        p += __shfl_xor(p, 2);
        p += __shfl_xor(p, 1);
        if (k0 == 0) ang[q] = tanhf(p + bb[q]);
    }
    #pragma unroll
    for (int r = 0; r < 4; ++r) {
        int idx = lane + 64 * r;
        psi[idx] = make_float2(idx == 0 ? 1.f : 0.f, 0.f);
    }
    __syncthreads();

    const float PI_F = 3.14159265358979323846f;

    for (int q = 0; q < 8; ++q) {
        float half = ang[q] * PI_F * 0.5f;
        float cv = cosf(half), sv = sinf(half);
        apply1q(psi, lane, q,
                make_float2(cv, 0.f), make_float2(0.f, -sv),
                make_float2(0.f, -sv), make_float2(cv, 0.f));
    }

    for (int l = 0; l < 3; ++l) {
        for (int q = 0; q < 8; ++q) {
            float phi = qw[(l * 8 + q) * 3 + 0];
            float th  = qw[(l * 8 + q) * 3 + 1];
            float om  = qw[(l * 8 + q) * 3 + 2];
            float ct = cosf(0.5f * th), st = sinf(0.5f * th);
            float A = 0.5f * (phi + om), D = 0.5f * (phi - om);
            float cA = cosf(A), sA = sinf(A), cD = cosf(D), sD = sinf(D);
            apply1q(psi, lane, q,
                    make_float2(ct * cA, -ct * sA), make_float2(-st * cD, -st * sD),
                    make_float2(st * cD, -st * sD), make_float2(ct * cA,  ct * sA));
        }
        int stride = l + 1;
        for (int q = 0; q + stride < 8; ++q) {
            int cbit = 1 << (7 - q);
            int tbit = 1 << (7 - (q + stride));
            #pragma unroll
            for (int r = 0; r < 4; ++r) {
                int idx = lane + 64 * r;
                if ((idx & cbit) && !(idx & tbit)) {
                    int j = idx | tbit;
                    float2 tmp = psi[idx];
                    psi[idx] = psi[j];
                    psi[j] = tmp;
                }
            }
            __syncthreads();
        }
    }

    float z[8];
    #pragma unroll
    for (int q = 0; q < 8; ++q) z[q] = 0.f;
    #pragma unroll
    for (int r = 0; r < 4; ++r) {
        int idx = lane + 64 * r;
        float2 a = psi[idx];
        float pr = a.x * a.x + a.y * a.y;
        #pragma unroll
        for (int q = 0; q < 8; ++q)
            z[q] += (idx & (1 << (7 - q))) ? -pr : pr;
    }
    #pragma unroll
    for (int q = 0; q < 8; ++q) {
        #pragma unroll
        for (int off = 32; off; off >>= 1) z[q] += __shfl_xor(z[q], off);
    }
    if (lane == 0) {
        #pragma unroll
        for (int c = 0; c < 3; ++c) {
            float acc = cb[c];
            #pragma unroll
            for (int q = 0; q < 8; ++q) acc = fmaf(z[q], cw[c * 8 + q], acc);
            out[s * 3 + c] = acc;
        }
    }
}

extern "C" void kernel_launch(void* const* d_in, const int* in_sizes, int n_in,
                              void* d_out, int out_size, void* d_ws, size_t ws_size,
                              hipStream_t stream)
{
    (void)in_sizes; (void)n_in; (void)out_size;
    const float* x0  = (const float*)d_in[0];
    const float* x1  = (const float*)d_in[1];
    const float* x2  = (const float*)d_in[2];
    const float* x3  = (const float*)d_in[3];
    const float* c1w = (const float*)d_in[4];
    const float* c1b = (const float*)d_in[5];
    const float* c2w = (const float*)d_in[6];
    const float* c2b = (const float*)d_in[7];
    const float* wih = (const float*)d_in[8];
    const float* whh = (const float*)d_in[9];
    const float* bih = (const float*)d_in[10];
    const float* bhh = (const float*)d_in[11];
    const float* bw  = (const float*)d_in[12];
    const float* bb  = (const float*)d_in[13];
    const float* qw  = (const float*)d_in[14];
    const float* cw  = (const float*)d_in[15];
    const float* cb  = (const float*)d_in[16];

    const size_t state_b = 4ULL * BATCH * 64ULL * 4ULL;       // 2 MB
    const size_t feats_b = 4ULL * BATCH * 32ULL * 4ULL;       // 1 MB
    const size_t per_t   = 4ULL * 2048ULL * 32ULL * 4ULL;     // 1 MB/step (hi+lo)

    int Tseg = 0;
    for (int cand = 512; cand >= 32; cand >>= 1) {
        if ((size_t)cand * per_t + state_b + feats_b <= ws_size) { Tseg = cand; break; }
    }

    if (Tseg > 0) {
        size_t seg_elems = (size_t)Tseg * 4ULL * 2048ULL * 32ULL;
        unsigned short* seqh = (unsigned short*)d_ws;
        unsigned short* seql = seqh + seg_elems;
        float* state = (float*)((char*)d_ws + 2ULL * seg_elems * 2ULL);
        float* feats = (float*)((char*)state + state_b);

        for (int t0 = 0; t0 < TSTEPS; t0 += Tseg) {
            frontend_kernel<<<dim3(BATCH, 4 * (Tseg / CH)), 64, 0, stream>>>(
                x0, x1, x2, x3, c1w, c1b, c2w, c2b, seqh, seql, t0, Tseg);
            lstm_mfma_kernel<<<dim3(BATCH / 32, 4), 64, 0, stream>>>(
                seqh, seql, wih, whh, bih, bhh, state, feats, t0, Tseg);
        }
        tail_kernel<<<BATCH, 64, 0, stream>>>(
            feats, bw, bb, qw, cw, cb, (float*)d_out);
    } else {
        float* feats = (float*)d_ws;
        branch_fallback<<<dim3(BATCH, 4), 64, 0, stream>>>(
            x0, x1, x2, x3, c1w, c1b, c2w, c2b, wih, whh, bih, bhh, feats);
        tail_kernel<<<BATCH, 64, 0, stream>>>(
            feats, bw, bb, qw, cw, cb, (float*)d_out);
    }
}

// Round 15
// 1534.734 us; speedup vs baseline: 1.6440x; 1.6440x over previous
//
#include <hip/hip_runtime.h>
#include <hip/hip_bf16.h>

#define BATCH 2048
#define LSIG 2048
#define TSTEPS 512
#define CH 16
#define NCHUNK (TSTEPS / CH)

typedef float v2f __attribute__((ext_vector_type(2)));
typedef float v4f __attribute__((ext_vector_type(4)));
typedef __bf16 b16x8 __attribute__((ext_vector_type(8)));
typedef float f32x4 __attribute__((ext_vector_type(4)));

#define PKFMA(d, a, b) asm("v_pk_fma_f32 %0, %1, %2, %0" : "+v"(d) : "v"(a), "v"(b))

__device__ __forceinline__ float sigf(float x) {
    return __fdividef(1.f, 1.f + __expf(-x));
}
__device__ __forceinline__ float tanhfast(float x) {
    return 1.f - __fdividef(2.f, __expf(2.f * x) + 1.f);
}
__device__ __forceinline__ unsigned short bf16rne(float f) {
    unsigned u = __float_as_uint(f);
    return (unsigned short)((u + 0x7FFFu + ((u >> 16) & 1u)) >> 16);
}
__device__ __forceinline__ int swz(int co) {
    return (co < 16) ? ((co >> 2) * 8 + (co & 3))
                     : (((co >> 2) - 4) * 8 + 4 + (co & 3));
}

// ============ K1: conv front-end for ONE chunk -> seq hi/lo planes =========
__global__ __launch_bounds__(64) void frontend_kernel(
    const float* __restrict__ x0, const float* __restrict__ x1,
    const float* __restrict__ x2, const float* __restrict__ x3,
    const float* __restrict__ c1w, const float* __restrict__ c1b,
    const float* __restrict__ c2w, const float* __restrict__ c2b,
    unsigned short* __restrict__ seqh, unsigned short* __restrict__ seql,
    int t0, int Tseg)
{
    const int s    = blockIdx.x;
    const int br   = blockIdx.y & 3;
    const int ck   = blockIdx.y >> 2;
    const int lane = threadIdx.x;
    const float* xg = (br == 0) ? x0 : (br == 1) ? x1 : (br == 2) ? x2 : x3;

    __shared__ float xs_c[70];
    __shared__ float p1buf[34][16];

    const int ci = lane & 15;
    const int co = lane & 31;
    const int hf = lane >> 5;
    const int sp = swz(co);
    const int tc0 = t0 + ck * CH;
    const int lt0 = ck * CH;

    const float w10 = c1w[br * 48 + ci * 3 + 0];
    const float w11 = c1w[br * 48 + ci * 3 + 1];
    const float w12 = c1w[br * 48 + ci * 3 + 2];
    const float b1v = c1b[br * 16 + ci];

    float wt[24];
    {
        const v4f* p = (const v4f*)(c2w + br * 1536 + co * 48 + hf * 24);
        #pragma unroll
        for (int i = 0; i < 6; ++i) ((v4f*)wt)[i] = p[i];
    }
    v4f w2p[3][2];
    #pragma unroll
    for (int k = 0; k < 3; ++k)
        #pragma unroll
        for (int h2 = 0; h2 < 2; ++h2)
            w2p[k][h2] = (v4f){ wt[(h2 * 4 + 0) * 3 + k], wt[(h2 * 4 + 1) * 3 + k],
                                wt[(h2 * 4 + 2) * 3 + k], wt[(h2 * 4 + 3) * 3 + k] };
    const float b2v = c2b[br * 32 + co];

    {
        int g = 4 * tc0 - 3 + lane;
        xs_c[lane] = ((unsigned)g < (unsigned)LSIG) ? xg[(size_t)s * LSIG + g] : 0.f;
        if (lane < 6) {
            int g2 = 4 * tc0 + 61 + lane;
            xs_c[64 + lane] = ((unsigned)g2 < (unsigned)LSIG) ? xg[(size_t)s * LSIG + g2] : 0.f;
        }
    }
    __syncthreads();

    #pragma unroll 1
    for (int it = 0; it < 9; ++it) {
        int idx = it * 64 + lane;
        if (idx < 34 * 16) {
            int pl = idx >> 4;
            float xa = xs_c[2 * pl + 0], xb = xs_c[2 * pl + 1];
            float xc = xs_c[2 * pl + 2], xd = xs_c[2 * pl + 3];
            float a0 = fmaf(xc, w12, fmaf(xb, w11, fmaf(xa, w10, b1v)));
            float a1 = fmaf(xd, w12, fmaf(xc, w11, fmaf(xb, w10, b1v)));
            float v = fmaxf(fmaxf(a0, a1), 0.f);
            int p1g = 2 * tc0 - 1 + pl;
            v = ((unsigned)p1g < (unsigned)(LSIG / 2)) ? v : 0.f;
            p1buf[pl][idx & 15] = v;
        }
    }
    __syncthreads();

    {
        const v4f* pbase = (const v4f*)&p1buf[0][0];
        const int h2o = hf * 2;
        v4f r0a = pbase[0 * 4 + h2o], r0b = pbase[0 * 4 + h2o + 1];
        v4f r1a = pbase[1 * 4 + h2o], r1b = pbase[1 * 4 + h2o + 1];
        v4f r2a = pbase[2 * 4 + h2o], r2b = pbase[2 * 4 + h2o + 1];
        v4f r3a = pbase[3 * 4 + h2o], r3b = pbase[3 * 4 + h2o + 1];
        #pragma unroll 1
        for (int tl = 0; tl < CH; ++tl) {
            v2f aA = {0.f, 0.f}, aB = {0.f, 0.f};
            PKFMA(aA, r0a.xy, w2p[0][0].xy); PKFMA(aA, r0a.zw, w2p[0][0].zw);
            PKFMA(aA, r0b.xy, w2p[0][1].xy); PKFMA(aA, r0b.zw, w2p[0][1].zw);
            PKFMA(aA, r1a.xy, w2p[1][0].xy); PKFMA(aA, r1a.zw, w2p[1][0].zw);
            PKFMA(aA, r1b.xy, w2p[1][1].xy); PKFMA(aA, r1b.zw, w2p[1][1].zw);
            PKFMA(aA, r2a.xy, w2p[2][0].xy); PKFMA(aA, r2a.zw, w2p[2][0].zw);
            PKFMA(aA, r2b.xy, w2p[2][1].xy); PKFMA(aA, r2b.zw, w2p[2][1].zw);
            PKFMA(aB, r1a.xy, w2p[0][0].xy); PKFMA(aB, r1a.zw, w2p[0][0].zw);
            PKFMA(aB, r1b.xy, w2p[0][1].xy); PKFMA(aB, r1b.zw, w2p[0][1].zw);
            PKFMA(aB, r2a.xy, w2p[1][0].xy); PKFMA(aB, r2a.zw, w2p[1][0].zw);
            PKFMA(aB, r2b.xy, w2p[1][1].xy); PKFMA(aB, r2b.zw, w2p[1][1].zw);
            PKFMA(aB, r3a.xy, w2p[2][0].xy); PKFMA(aB, r3a.zw, w2p[2][0].zw);
            PKFMA(aB, r3b.xy, w2p[2][1].xy); PKFMA(aB, r3b.zw, w2p[2][1].zw);
            float sA = aA.x + aA.y, sB = aB.x + aB.y;
            sA += __shfl_xor(sA, 32);
            sB += __shfl_xor(sB, 32);
            float sv = fmaxf(fmaxf(sA, sB) + b2v, 0.f);
            unsigned short hb = bf16rne(sv);
            float hif = __uint_as_float(((unsigned)hb) << 16);
            unsigned short lb = bf16rne(sv - hif);
            size_t off = (((size_t)br * Tseg + (lt0 + tl)) * 2048 + s) * 32 + sp;
            if (hf == 0) seqh[off] = hb;
            else         seql[off] = lb;
            r0a = r2a; r0b = r2b; r1a = r3a; r1b = r3b;
            if (tl < CH - 1) {
                r2a = pbase[(2 * tl + 4) * 4 + h2o]; r2b = pbase[(2 * tl + 4) * 4 + h2o + 1];
                r3a = pbase[(2 * tl + 5) * 4 + h2o]; r3b = pbase[(2 * tl + 5) * 4 + h2o + 1];
            }
        }
    }
}

// ============ K2: MFMA LSTM, 16 samples/wave (R12 structure, tuned) ========
// D layout (verified R12): col=lane&15 (sample), row=4q+r -> lane holds
// i,f,g,o of units {4q+r,16+4q+r}; that IS the next step's B-frag.
// R15 changes vs R12: bias in REGISTERS (no per-step LDS reads/lgkm waits);
// acc chains IN-PLACE on xacc (saves 32 VGPR); 2-step-ahead x prefetch with
// pointer-bump addressing (covers L3/HBM latency; no 64-bit mul per step).
__global__ __launch_bounds__(64, 1) void lstm_mfma_kernel(
    const unsigned short* __restrict__ seqh, const unsigned short* __restrict__ seql,
    const float* __restrict__ wih, const float* __restrict__ whh,
    const float* __restrict__ bih, const float* __restrict__ bhh,
    float* __restrict__ state, float* __restrict__ feats,
    int t0, int Tseg)
{
    const int s0   = blockIdx.x * 16;
    const int br   = blockIdx.y;
    const int lane = threadIdx.x;
    const int c    = lane & 15;   // sample col
    const int q    = lane >> 4;

    // ---- bias in registers (D layout: gate = 16n + 4q + r) ----
    f32x4 bias[8];
    #pragma unroll
    for (int n = 0; n < 8; ++n)
        #pragma unroll
        for (int r = 0; r < 4; ++r) {
            int g = 16 * n + 4 * q + r;
            bias[n][r] = bih[br * 128 + g] + bhh[br * 128 + g];
        }

    // ---- weight A-frags: row = c (gate 16n+c), k elems {4q+j} u {16+4q+j} ----
    b16x8 wihhi[8], wihlo[8], whhhi[8], whhlo[8];
    #pragma unroll
    for (int n = 0; n < 8; ++n) {
        const int gr = 16 * n + c;
        const float* pi = wih + (size_t)br * 4096 + (size_t)gr * 32;
        const float* ph = whh + (size_t)br * 4096 + (size_t)gr * 32;
        v4f ia = *(const v4f*)(pi + 4 * q);
        v4f ib = *(const v4f*)(pi + 16 + 4 * q);
        v4f ha = *(const v4f*)(ph + 4 * q);
        v4f hb = *(const v4f*)(ph + 16 + 4 * q);
        #pragma unroll
        for (int j = 0; j < 4; ++j) {
            __bf16 t;
            t = (__bf16)ia[j]; wihhi[n][j]     = t; wihlo[n][j]     = (__bf16)(ia[j] - (float)t);
            t = (__bf16)ib[j]; wihhi[n][4 + j] = t; wihlo[n][4 + j] = (__bf16)(ib[j] - (float)t);
            t = (__bf16)ha[j]; whhhi[n][j]     = t; whhlo[n][j]     = (__bf16)(ha[j] - (float)t);
            t = (__bf16)hb[j]; whhhi[n][4 + j] = t; whhlo[n][4 + j] = (__bf16)(hb[j] - (float)t);
        }
    }

    // ---- state: init or restore ----
    b16x8 bhh_f, bhl_f;
    float cst[2][4];
    if (t0 == 0) {
        #pragma unroll
        for (int j = 0; j < 8; ++j) { bhh_f[j] = (__bf16)0.f; bhl_f[j] = (__bf16)0.f; }
        #pragma unroll
        for (int hh = 0; hh < 2; ++hh)
            #pragma unroll
            for (int r = 0; r < 4; ++r) cst[hh][r] = 0.f;
    } else {
        const float* st = state + (((size_t)br * BATCH + s0 + c) * 2) * 32;
        #pragma unroll
        for (int hh = 0; hh < 2; ++hh)
            #pragma unroll
            for (int r = 0; r < 4; ++r) {
                int u = 16 * hh + 4 * q + r;
                float hv = st[u];
                __bf16 hb2 = (__bf16)hv;
                bhh_f[hh * 4 + r] = hb2;
                bhl_f[hh * 4 + r] = (__bf16)(hv - (float)hb2);
                cst[hh][r] = st[32 + u];
            }
    }

    // ---- x pointers (bump per step) ----
    const size_t xbase = ((size_t)br * Tseg * 2048 + s0 + c) * 32 + (size_t)q * 8;
    const size_t xstep = 2048 * 32;
    const unsigned short* ph = seqh + xbase;
    const unsigned short* pl = seql + xbase;

    // prologue: xacc = bias + Wih*x(0); prefetch x(1)
    f32x4 xacc[8];
    b16x8 nh1, nl1;
    {
        b16x8 x0h = *(const b16x8*)ph;
        b16x8 x0l = *(const b16x8*)pl;
        #pragma unroll
        for (int n = 0; n < 8; ++n) {
            xacc[n] = __builtin_amdgcn_mfma_f32_16x16x32_bf16(wihhi[n], x0h, bias[n], 0, 0, 0);
            xacc[n] = __builtin_amdgcn_mfma_f32_16x16x32_bf16(wihhi[n], x0l, xacc[n], 0, 0, 0);
            xacc[n] = __builtin_amdgcn_mfma_f32_16x16x32_bf16(wihlo[n], x0h, xacc[n], 0, 0, 0);
        }
        nh1 = *(const b16x8*)(ph + xstep);
        nl1 = *(const b16x8*)(pl + xstep);
    }

    #pragma unroll 1
    for (int t = 0; t < Tseg; ++t) {
        const bool last = (t0 + t == TSTEPS - 1);
        // issue x(t+2) load early — 2 steps of latency cover
        b16x8 nh2, nl2;
        if (t + 2 < Tseg) {
            nh2 = *(const b16x8*)(ph + (size_t)(t + 2) * xstep);
            nl2 = *(const b16x8*)(pl + (size_t)(t + 2) * xstep);
        }

        // h-part: 3 chained MFMAs per n, in place on pipelined xacc
        #pragma unroll
        for (int n = 0; n < 8; ++n) {
            xacc[n] = __builtin_amdgcn_mfma_f32_16x16x32_bf16(whhhi[n], bhh_f, xacc[n], 0, 0, 0);
            xacc[n] = __builtin_amdgcn_mfma_f32_16x16x32_bf16(whhhi[n], bhl_f, xacc[n], 0, 0, 0);
            xacc[n] = __builtin_amdgcn_mfma_f32_16x16x32_bf16(whhlo[n], bhh_f, xacc[n], 0, 0, 0);
        }

        // activations + cell update (lane-local units {4q+r, 16+4q+r})
        #pragma unroll
        for (int hh = 0; hh < 2; ++hh) {
            #pragma unroll
            for (int r = 0; r < 4; ++r) {
                float gi = xacc[0 + hh][r];
                float gf = xacc[2 + hh][r];
                float gg = xacc[4 + hh][r];
                float go = xacc[6 + hh][r];
                float si = sigf(gi);
                float sf = sigf(gf);
                float tg = tanhfast(gg);
                float so = sigf(go);
                float cc = fmaf(sf, cst[hh][r], si * tg);
                cst[hh][r] = cc;
                float hv = so * tanhfast(cc);
                __bf16 hb2 = (__bf16)hv;
                bhh_f[hh * 4 + r] = hb2;
                bhl_f[hh * 4 + r] = (__bf16)(hv - (float)hb2);
                if (last)
                    feats[((size_t)br * BATCH + s0 + c) * 32 + 16 * hh + 4 * q + r] = hv;
            }
        }

        // xacc for step t+1 from x(t+1) (off the h-critical-path)
        if (t < Tseg - 1) {
            #pragma unroll
            for (int n = 0; n < 8; ++n) {
                xacc[n] = __builtin_amdgcn_mfma_f32_16x16x32_bf16(wihhi[n], nh1, bias[n], 0, 0, 0);
                xacc[n] = __builtin_amdgcn_mfma_f32_16x16x32_bf16(wihhi[n], nl1, xacc[n], 0, 0, 0);
                xacc[n] = __builtin_amdgcn_mfma_f32_16x16x32_bf16(wihlo[n], nh1, xacc[n], 0, 0, 0);
            }
            nh1 = nh2; nl1 = nl2;
        }
    }

    // save state for next segment
    if (t0 + Tseg < TSTEPS) {
        float* st = state + (((size_t)br * BATCH + s0 + c) * 2) * 32;
        #pragma unroll
        for (int hh = 0; hh < 2; ++hh)
            #pragma unroll
            for (int r = 0; r < 4; ++r) {
                int u = 16 * hh + 4 * q + r;
                st[u]      = (float)bhh_f[hh * 4 + r] + (float)bhl_f[hh * 4 + r];
                st[32 + u] = cst[hh][r];
            }
    }
}

// ============ fallback: R7 monolithic branch kernel ========================
__global__ __launch_bounds__(64, 2) void branch_fallback(
    const float* __restrict__ x0, const float* __restrict__ x1,
    const float* __restrict__ x2, const float* __restrict__ x3,
    const float* __restrict__ c1w, const float* __restrict__ c1b,
    const float* __restrict__ c2w, const float* __restrict__ c2b,
    const float* __restrict__ wih, const float* __restrict__ whh,
    const float* __restrict__ bih, const float* __restrict__ bhh,
    float* __restrict__ feats)
{
    const int s    = blockIdx.x;
    const int br   = blockIdx.y;
    const int lane = threadIdx.x;
    const float* xg = (br == 0) ? x0 : (br == 1) ? x1 : (br == 2) ? x2 : x3;

    __shared__ float xs_c[70];
    __shared__ float p1buf[34][16];
    __shared__ float seqb[CH][32];
    __shared__ float hb[2][32];

    const int ci = lane & 15;
    const int co = lane & 31;
    const int hf = lane >> 5;

    const float bs0 = bih[br * 128 + lane]      + bhh[br * 128 + lane];
    const float bs1 = bih[br * 128 + lane + 64] + bhh[br * 128 + lane + 64];

    if (lane < 32) hb[0][lane] = 0.f;
    float c_state = 0.f;

    #pragma unroll 1
    for (int chk = 0; chk < NCHUNK; ++chk) {
        const int tc0 = chk * CH;
        {
            int g = 4 * tc0 - 3 + lane;
            xs_c[lane] = ((unsigned)g < (unsigned)LSIG) ? xg[(size_t)s * LSIG + g] : 0.f;
            if (lane < 6) {
                int g2 = 4 * tc0 + 61 + lane;
                xs_c[64 + lane] = ((unsigned)g2 < (unsigned)LSIG) ? xg[(size_t)s * LSIG + g2] : 0.f;
            }
        }
        const float* pc1 = c1w + br * 48 + ci * 3;  asm volatile("" : "+v"(pc1));
        const float w10 = pc1[0], w11 = pc1[1], w12 = pc1[2];
        const float* pb1 = c1b + br * 16 + ci;      asm volatile("" : "+v"(pb1));
        const float b1v = pb1[0];
        const float* pc2 = c2w + br * 1536 + co * 48 + hf * 24;
        asm volatile("" : "+v"(pc2));
        float wt[24];
        #pragma unroll
        for (int i = 0; i < 6; ++i) ((v4f*)wt)[i] = ((const v4f*)pc2)[i];
        v4f w2p[3][2];
        #pragma unroll
        for (int k = 0; k < 3; ++k)
            #pragma unroll
            for (int h2 = 0; h2 < 2; ++h2)
                w2p[k][h2] = (v4f){ wt[(h2 * 4 + 0) * 3 + k], wt[(h2 * 4 + 1) * 3 + k],
                                    wt[(h2 * 4 + 2) * 3 + k], wt[(h2 * 4 + 3) * 3 + k] };
        const float* pb2 = c2b + br * 32 + co;      asm volatile("" : "+v"(pb2));
        const float b2v = pb2[0];
        __syncthreads();
        #pragma unroll 1
        for (int it = 0; it < 9; ++it) {
            int idx = it * 64 + lane;
            if (idx < 34 * 16) {
                int pl = idx >> 4;
                float xa = xs_c[2 * pl + 0], xb = xs_c[2 * pl + 1];
                float xc = xs_c[2 * pl + 2], xd = xs_c[2 * pl + 3];
                float a0 = fmaf(xc, w12, fmaf(xb, w11, fmaf(xa, w10, b1v)));
                float a1 = fmaf(xd, w12, fmaf(xc, w11, fmaf(xb, w10, b1v)));
                float v = fmaxf(fmaxf(a0, a1), 0.f);
                int p1g = 2 * tc0 - 1 + pl;
                v = ((unsigned)p1g < (unsigned)(LSIG / 2)) ? v : 0.f;
                p1buf[pl][idx & 15] = v;
            }
        }
        __syncthreads();
        {
            const v4f* pbase = (const v4f*)&p1buf[0][0];
            const int h2o = hf * 2;
            v4f r0a = pbase[0 * 4 + h2o], r0b = pbase[0 * 4 + h2o + 1];
            v4f r1a = pbase[1 * 4 + h2o], r1b = pbase[1 * 4 + h2o + 1];
            v4f r2a = pbase[2 * 4 + h2o], r2b = pbase[2 * 4 + h2o + 1];
            v4f r3a = pbase[3 * 4 + h2o], r3b = pbase[3 * 4 + h2o + 1];
            #pragma unroll 1
            for (int tl = 0; tl < CH; ++tl) {
                v2f aA = {0.f, 0.f}, aB = {0.f, 0.f};
                PKFMA(aA, r0a.xy, w2p[0][0].xy); PKFMA(aA, r0a.zw, w2p[0][0].zw);
                PKFMA(aA, r0b.xy, w2p[0][1].xy); PKFMA(aA, r0b.zw, w2p[0][1].zw);
                PKFMA(aA, r1a.xy, w2p[1][0].xy); PKFMA(aA, r1a.zw, w2p[1][0].zw);
                PKFMA(aA, r1b.xy, w2p[1][1].xy); PKFMA(aA, r1b.zw, w2p[1][1].zw);
                PKFMA(aA, r2a.xy, w2p[2][0].xy); PKFMA(aA, r2a.zw, w2p[2][0].zw);
                PKFMA(aA, r2b.xy, w2p[2][1].xy); PKFMA(aA, r2b.zw, w2p[2][1].zw);
                PKFMA(aB, r1a.xy, w2p[0][0].xy); PKFMA(aB, r1a.zw, w2p[0][0].zw);
                PKFMA(aB, r1b.xy, w2p[0][1].xy); PKFMA(aB, r1b.zw, w2p[0][1].zw);
                PKFMA(aB, r2a.xy, w2p[1][0].xy); PKFMA(aB, r2a.zw, w2p[1][0].zw);
                PKFMA(aB, r2b.xy, w2p[1][1].xy); PKFMA(aB, r2b.zw, w2p[1][1].zw);
                PKFMA(aB, r3a.xy, w2p[2][0].xy); PKFMA(aB, r3a.zw, w2p[2][0].zw);
                PKFMA(aB, r3b.xy, w2p[2][1].xy); PKFMA(aB, r3b.zw, w2p[2][1].zw);
                float sA = aA.x + aA.y, sB = aB.x + aB.y;
                sA += __shfl_xor(sA, 32);
                sB += __shfl_xor(sB, 32);
                if (hf == 0)
                    seqb[tl][co] = fmaxf(fmaxf(sA, sB) + b2v, 0.f);
                r0a = r2a; r0b = r2b; r1a = r3a; r1b = r3b;
                if (tl < CH - 1) {
                    r2a = pbase[(2 * tl + 4) * 4 + h2o]; r2b = pbase[(2 * tl + 4) * 4 + h2o + 1];
                    r3a = pbase[(2 * tl + 5) * 4 + h2o]; r3b = pbase[(2 * tl + 5) * 4 + h2o + 1];
                }
            }
        }
        __syncthreads();
        float gpx0[CH], gpx1[CH];
        {
            const float* pwi = wih + (size_t)br * 4096 + (size_t)lane * 32;
            asm volatile("" : "+v"(pwi));
            v4f wiA[8], wiB[8];
            #pragma unroll
            for (int j = 0; j < 8; ++j) {
                wiA[j] = ((const v4f*)pwi)[j];
                wiB[j] = ((const v4f*)(pwi + 64 * 32))[j];
            }
            #pragma unroll
            for (int tl = 0; tl < CH; ++tl) {
                const v4f* xq = (const v4f*)&seqb[tl][0];
                v2f aA = {0.f, 0.f}, aB = {0.f, 0.f};
                #pragma unroll
                for (int j = 0; j < 8; ++j) {
                    v4f xv = xq[j];
                    PKFMA(aA, xv.xy, wiA[j].xy); PKFMA(aA, xv.zw, wiA[j].zw);
                    PKFMA(aB, xv.xy, wiB[j].xy); PKFMA(aB, xv.zw, wiB[j].zw);
                }
                gpx0[tl] = aA.x + aA.y;
                gpx1[tl] = aB.x + aB.y;
            }
        }
        {
            const float* pwh = whh + (size_t)br * 4096 + (size_t)lane * 32;
            asm volatile("" : "+v"(pwh));
            v4f whA[8], whB[8];
            #pragma unroll
            for (int j = 0; j < 8; ++j) {
                whA[j] = ((const v4f*)pwh)[j];
                whB[j] = ((const v4f*)(pwh + 64 * 32))[j];
            }
            #pragma unroll
            for (int tl = 0; tl < CH; ++tl) {
                __syncthreads();
                const int p = (tc0 + tl) & 1;
                const v4f* hq = (const v4f*)&hb[p][0];
                v2f aA = {0.f, 0.f}, aB = {0.f, 0.f};
                #pragma unroll
                for (int j = 0; j < 8; ++j) {
                    v4f hv = hq[j];
                    PKFMA(aA, hv.xy, whA[j].xy); PKFMA(aA, hv.zw, whA[j].zw);
                    PKFMA(aB, hv.xy, whB[j].xy); PKFMA(aB, hv.zw, whB[j].zw);
                }
                float g0 = bs0 + gpx0[tl] + aA.x + aA.y;
                float g1 = bs1 + gpx1[tl] + aB.x + aB.y;
                float a0 = sigf(g0);
                float earg = (lane < 32) ? 2.f * g1 : -g1;
                float e1 = __expf(fminf(earg, 80.f));
                float num = (lane < 32) ? e1 - 1.f : 1.f;
                float a1 = __fdividef(num, e1 + 1.f);
                float fa = __shfl_xor(a0, 32);
                float oa = __shfl_xor(a1, 32);
                if (lane < 32) {
                    c_state = fmaf(fa, c_state, a0 * a1);
                    hb[p ^ 1][lane] = oa * tanhfast(c_state);
                }
            }
        }
    }
    __syncthreads();
    if (lane < 32)
        feats[((size_t)br * BATCH + s) * 32 + lane] = hb[0][lane];
}

// ---------------- tail: bottleneck + 8-qubit statevector + classifier -------

__device__ __forceinline__ void apply1q(float2* psi, int lane, int q,
                                        float2 g00, float2 g01,
                                        float2 g10, float2 g11)
{
    const int shift = 7 - q;
    const int right = 1 << shift;
    #pragma unroll
    for (int pp = 0; pp < 2; ++pp) {
        int p  = lane + 64 * pp;
        int l  = p >> shift;
        int r  = p & (right - 1);
        int i0 = (l << (shift + 1)) + r;
        int i1 = i0 + right;
        float2 a = psi[i0], b = psi[i1];
        float2 n0 = make_float2(g00.x * a.x - g00.y * a.y + g01.x * b.x - g01.y * b.y,
                                g00.x * a.y + g00.y * a.x + g01.x * b.y + g01.y * b.x);
        float2 n1 = make_float2(g10.x * a.x - g10.y * a.y + g11.x * b.x - g11.y * b.y,
                                g10.x * a.y + g10.y * a.x + g11.x * b.y + g11.y * b.x);
        psi[i0] = n0;
        psi[i1] = n1;
    }
    __syncthreads();
}

__global__ __launch_bounds__(64) void tail_kernel(
    const float* __restrict__ feats, const float* __restrict__ bw,
    const float* __restrict__ bb, const float* __restrict__ qw,
    const float* __restrict__ cw, const float* __restrict__ cb,
    float* __restrict__ out)
{
    const int s    = blockIdx.x;
    const int lane = threadIdx.x;

    __shared__ float comb[128];
    __shared__ float2 psi[256];
    __shared__ float ang[8];

    comb[lane]      = feats[(size_t)(lane >> 5) * (BATCH * 32) + (size_t)s * 32 + (lane & 31)];
    comb[lane + 64] = feats[(size_t)((lane + 64) >> 5) * (BATCH * 32) + (size_t)s * 32 + (lane & 31)];
    __syncthreads();

    {
        int q = lane >> 3, k0 = lane & 7;
        float p = 0.f;
        #pragma unroll
        for (int i = 0; i < 16; ++i) {
            int k = k0 + 8 * i;
            p = fmaf(comb[k], bw[q * 128 + k], p);
        }
        p += __shfl_xor(p, 4);
        p += __shfl_xor(p, 2);
        p += __shfl_xor(p, 1);
        if (k0 == 0) ang[q] = tanhf(p + bb[q]);
    }
    #pragma unroll
    for (int r = 0; r < 4; ++r) {
        int idx = lane + 64 * r;
        psi[idx] = make_float2(idx == 0 ? 1.f : 0.f, 0.f);
    }
    __syncthreads();

    const float PI_F = 3.14159265358979323846f;

    for (int q = 0; q < 8; ++q) {
        float half = ang[q] * PI_F * 0.5f;
        float cv = cosf(half), sv = sinf(half);
        apply1q(psi, lane, q,
                make_float2(cv, 0.f), make_float2(0.f, -sv),
                make_float2(0.f, -sv), make_float2(cv, 0.f));
    }

    for (int l = 0; l < 3; ++l) {
        for (int q = 0; q < 8; ++q) {
            float phi = qw[(l * 8 + q) * 3 + 0];
            float th  = qw[(l * 8 + q) * 3 + 1];
            float om  = qw[(l * 8 + q) * 3 + 2];
            float ct = cosf(0.5f * th), st = sinf(0.5f * th);
            float A = 0.5f * (phi + om), D = 0.5f * (phi - om);
            float cA = cosf(A), sA = sinf(A), cD = cosf(D), sD = sinf(D);
            apply1q(psi, lane, q,
                    make_float2(ct * cA, -ct * sA), make_float2(-st * cD, -st * sD),
                    make_float2(st * cD, -st * sD), make_float2(ct * cA,  ct * sA));
        }
        int stride = l + 1;
        for (int q = 0; q + stride < 8; ++q) {
            int cbit = 1 << (7 - q);
            int tbit = 1 << (7 - (q + stride));
            #pragma unroll
            for (int r = 0; r < 4; ++r) {
                int idx = lane + 64 * r;
                if ((idx & cbit) && !(idx & tbit)) {
                    int j = idx | tbit;
                    float2 tmp = psi[idx];
                    psi[idx] = psi[j];
                    psi[j] = tmp;
                }
            }
            __syncthreads();
        }
    }

    float z[8];
    #pragma unroll
    for (int q = 0; q < 8; ++q) z[q] = 0.f;
    #pragma unroll
    for (int r = 0; r < 4; ++r) {
        int idx = lane + 64 * r;
        float2 a = psi[idx];
        float pr = a.x * a.x + a.y * a.y;
        #pragma unroll
        for (int q = 0; q < 8; ++q)
            z[q] += (idx & (1 << (7 - q))) ? -pr : pr;
    }
    #pragma unroll
    for (int q = 0; q < 8; ++q) {
        #pragma unroll
        for (int off = 32; off; off >>= 1) z[q] += __shfl_xor(z[q], off);
    }
    if (lane == 0) {
        #pragma unroll
        for (int c = 0; c < 3; ++c) {
            float acc = cb[c];
            #pragma unroll
            for (int q = 0; q < 8; ++q) acc = fmaf(z[q], cw[c * 8 + q], acc);
            out[s * 3 + c] = acc;
        }
    }
}

extern "C" void kernel_launch(void* const* d_in, const int* in_sizes, int n_in,
                              void* d_out, int out_size, void* d_ws, size_t ws_size,
                              hipStream_t stream)
{
    (void)in_sizes; (void)n_in; (void)out_size;
    const float* x0  = (const float*)d_in[0];
    const float* x1  = (const float*)d_in[1];
    const float* x2  = (const float*)d_in[2];
    const float* x3  = (const float*)d_in[3];
    const float* c1w = (const float*)d_in[4];
    const float* c1b = (const float*)d_in[5];
    const float* c2w = (const float*)d_in[6];
    const float* c2b = (const float*)d_in[7];
    const float* wih = (const float*)d_in[8];
    const float* whh = (const float*)d_in[9];
    const float* bih = (const float*)d_in[10];
    const float* bhh = (const float*)d_in[11];
    const float* bw  = (const float*)d_in[12];
    const float* bb  = (const float*)d_in[13];
    const float* qw  = (const float*)d_in[14];
    const float* cw  = (const float*)d_in[15];
    const float* cb  = (const float*)d_in[16];

    const size_t state_b = 4ULL * BATCH * 64ULL * 4ULL;       // 2 MB
    const size_t feats_b = 4ULL * BATCH * 32ULL * 4ULL;       // 1 MB
    const size_t per_t   = 4ULL * 2048ULL * 32ULL * 4ULL;     // 1 MB/step (hi+lo)

    int Tseg = 0;
    for (int cand = 512; cand >= 32; cand >>= 1) {
        if ((size_t)cand * per_t + state_b + feats_b <= ws_size) { Tseg = cand; break; }
    }

    if (Tseg > 0) {
        size_t seg_elems = (size_t)Tseg * 4ULL * 2048ULL * 32ULL;
        unsigned short* seqh = (unsigned short*)d_ws;
        unsigned short* seql = seqh + seg_elems;
        float* state = (float*)((char*)d_ws + 2ULL * seg_elems * 2ULL);
        float* feats = (float*)((char*)state + state_b);

        for (int t0 = 0; t0 < TSTEPS; t0 += Tseg) {
            frontend_kernel<<<dim3(BATCH, 4 * (Tseg / CH)), 64, 0, stream>>>(
                x0, x1, x2, x3, c1w, c1b, c2w, c2b, seqh, seql, t0, Tseg);
            lstm_mfma_kernel<<<dim3(BATCH / 16, 4), 64, 0, stream>>>(
                seqh, seql, wih, whh, bih, bhh, state, feats, t0, Tseg);
        }
        tail_kernel<<<BATCH, 64, 0, stream>>>(
            feats, bw, bb, qw, cw, cb, (float*)d_out);
    } else {
        float* feats = (float*)d_ws;
        branch_fallback<<<dim3(BATCH, 4), 64, 0, stream>>>(
            x0, x1, x2, x3, c1w, c1b, c2w, c2b, wih, whh, bih, bhh, feats);
        tail_kernel<<<BATCH, 64, 0, stream>>>(
            feats, bw, bb, qw, cw, cb, (float*)d_out);
    }
}

// Round 16
// 1497.162 us; speedup vs baseline: 1.6853x; 1.0251x over previous
//
#include <hip/hip_runtime.h>
#include <hip/hip_bf16.h>

#define BATCH 2048
#define LSIG 2048
#define TSTEPS 512
#define CH 16
#define NCHUNK (TSTEPS / CH)

typedef float v2f __attribute__((ext_vector_type(2)));
typedef float v4f __attribute__((ext_vector_type(4)));
typedef __bf16 b16x8 __attribute__((ext_vector_type(8)));
typedef float f32x4 __attribute__((ext_vector_type(4)));
typedef unsigned int u32x4 __attribute__((ext_vector_type(4)));

#define PKFMA(d, a, b) asm("v_pk_fma_f32 %0, %1, %2, %0" : "+v"(d) : "v"(a), "v"(b))

__device__ __forceinline__ float sigf(float x) {
    return __fdividef(1.f, 1.f + __expf(-x));
}
__device__ __forceinline__ float tanhfast(float x) {
    return 1.f - __fdividef(2.f, __expf(2.f * x) + 1.f);
}
__device__ __forceinline__ unsigned short bf16rne(float f) {
    unsigned u = __float_as_uint(f);
    return (unsigned short)((u + 0x7FFFu + ((u >> 16) & 1u)) >> 16);
}
__device__ __forceinline__ unsigned cvtpk_bf16(float a, float b) {
    unsigned d;
    asm("v_cvt_pk_bf16_f32 %0, %1, %2" : "=v"(d) : "v"(a), "v"(b));
    return d;
}
__device__ __forceinline__ int swz(int co) {
    return (co < 16) ? ((co >> 2) * 8 + (co & 3))
                     : (((co >> 2) - 4) * 8 + 4 + (co & 3));
}

// ============ K1: conv front-end, NCK chunks per block -> seq planes =======
// grid (BATCH, 4 * (Tseg/CH)/nck); blockIdx.y: br = y&3, cko = y>>2.
// Chunk loop amortizes the conv-weight prologue (R16).
__global__ __launch_bounds__(64) void frontend_kernel(
    const float* __restrict__ x0, const float* __restrict__ x1,
    const float* __restrict__ x2, const float* __restrict__ x3,
    const float* __restrict__ c1w, const float* __restrict__ c1b,
    const float* __restrict__ c2w, const float* __restrict__ c2b,
    unsigned short* __restrict__ seqh, unsigned short* __restrict__ seql,
    int t0, int Tseg, int nck)
{
    const int s    = blockIdx.x;
    const int br   = blockIdx.y & 3;
    const int cko  = blockIdx.y >> 2;
    const int lane = threadIdx.x;
    const float* xg = (br == 0) ? x0 : (br == 1) ? x1 : (br == 2) ? x2 : x3;

    __shared__ float xs_c[70];
    __shared__ float p1buf[34][16];

    const int ci = lane & 15;
    const int co = lane & 31;
    const int hf = lane >> 5;
    const int sp = swz(co);

    const float w10 = c1w[br * 48 + ci * 3 + 0];
    const float w11 = c1w[br * 48 + ci * 3 + 1];
    const float w12 = c1w[br * 48 + ci * 3 + 2];
    const float b1v = c1b[br * 16 + ci];

    float wt[24];
    {
        const v4f* p = (const v4f*)(c2w + br * 1536 + co * 48 + hf * 24);
        #pragma unroll
        for (int i = 0; i < 6; ++i) ((v4f*)wt)[i] = p[i];
    }
    v4f w2p[3][2];
    #pragma unroll
    for (int k = 0; k < 3; ++k)
        #pragma unroll
        for (int h2 = 0; h2 < 2; ++h2)
            w2p[k][h2] = (v4f){ wt[(h2 * 4 + 0) * 3 + k], wt[(h2 * 4 + 1) * 3 + k],
                                wt[(h2 * 4 + 2) * 3 + k], wt[(h2 * 4 + 3) * 3 + k] };
    const float b2v = c2b[br * 32 + co];

    #pragma unroll 1
    for (int ic = 0; ic < nck; ++ic) {
        const int ck  = cko * nck + ic;
        const int tc0 = t0 + ck * CH;   // global step base
        const int lt0 = ck * CH;        // segment-local step base

        __syncthreads();   // protect xs_c/p1buf from previous chunk's readers
        {
            int g = 4 * tc0 - 3 + lane;
            xs_c[lane] = ((unsigned)g < (unsigned)LSIG) ? xg[(size_t)s * LSIG + g] : 0.f;
            if (lane < 6) {
                int g2 = 4 * tc0 + 61 + lane;
                xs_c[64 + lane] = ((unsigned)g2 < (unsigned)LSIG) ? xg[(size_t)s * LSIG + g2] : 0.f;
            }
        }
        __syncthreads();

        // phase A: 34 x 16 pooled1 window
        #pragma unroll 1
        for (int it = 0; it < 9; ++it) {
            int idx = it * 64 + lane;
            if (idx < 34 * 16) {
                int pl = idx >> 4;
                float xa = xs_c[2 * pl + 0], xb = xs_c[2 * pl + 1];
                float xc = xs_c[2 * pl + 2], xd = xs_c[2 * pl + 3];
                float a0 = fmaf(xc, w12, fmaf(xb, w11, fmaf(xa, w10, b1v)));
                float a1 = fmaf(xd, w12, fmaf(xc, w11, fmaf(xb, w10, b1v)));
                float v = fmaxf(fmaxf(a0, a1), 0.f);
                int p1g = 2 * tc0 - 1 + pl;
                v = ((unsigned)p1g < (unsigned)(LSIG / 2)) ? v : 0.f;
                p1buf[pl][idx & 15] = v;
            }
        }
        __syncthreads();

        // phase B: conv2 + relu + pool2 -> seq planes (sliding row window)
        {
            const v4f* pbase = (const v4f*)&p1buf[0][0];
            const int h2o = hf * 2;
            v4f r0a = pbase[0 * 4 + h2o], r0b = pbase[0 * 4 + h2o + 1];
            v4f r1a = pbase[1 * 4 + h2o], r1b = pbase[1 * 4 + h2o + 1];
            v4f r2a = pbase[2 * 4 + h2o], r2b = pbase[2 * 4 + h2o + 1];
            v4f r3a = pbase[3 * 4 + h2o], r3b = pbase[3 * 4 + h2o + 1];
            #pragma unroll 1
            for (int tl = 0; tl < CH; ++tl) {
                v2f aA = {0.f, 0.f}, aB = {0.f, 0.f};
                PKFMA(aA, r0a.xy, w2p[0][0].xy); PKFMA(aA, r0a.zw, w2p[0][0].zw);
                PKFMA(aA, r0b.xy, w2p[0][1].xy); PKFMA(aA, r0b.zw, w2p[0][1].zw);
                PKFMA(aA, r1a.xy, w2p[1][0].xy); PKFMA(aA, r1a.zw, w2p[1][0].zw);
                PKFMA(aA, r1b.xy, w2p[1][1].xy); PKFMA(aA, r1b.zw, w2p[1][1].zw);
                PKFMA(aA, r2a.xy, w2p[2][0].xy); PKFMA(aA, r2a.zw, w2p[2][0].zw);
                PKFMA(aA, r2b.xy, w2p[2][1].xy); PKFMA(aA, r2b.zw, w2p[2][1].zw);
                PKFMA(aB, r1a.xy, w2p[0][0].xy); PKFMA(aB, r1a.zw, w2p[0][0].zw);
                PKFMA(aB, r1b.xy, w2p[0][1].xy); PKFMA(aB, r1b.zw, w2p[0][1].zw);
                PKFMA(aB, r2a.xy, w2p[1][0].xy); PKFMA(aB, r2a.zw, w2p[1][0].zw);
                PKFMA(aB, r2b.xy, w2p[1][1].xy); PKFMA(aB, r2b.zw, w2p[1][1].zw);
                PKFMA(aB, r3a.xy, w2p[2][0].xy); PKFMA(aB, r3a.zw, w2p[2][0].zw);
                PKFMA(aB, r3b.xy, w2p[2][1].xy); PKFMA(aB, r3b.zw, w2p[2][1].zw);
                float sA = aA.x + aA.y, sB = aB.x + aB.y;
                sA += __shfl_xor(sA, 32);
                sB += __shfl_xor(sB, 32);
                float sv = fmaxf(fmaxf(sA, sB) + b2v, 0.f);
                unsigned short hb = bf16rne(sv);
                float hif = __uint_as_float(((unsigned)hb) << 16);
                unsigned short lb = bf16rne(sv - hif);
                size_t off = (((size_t)br * Tseg + (lt0 + tl)) * 2048 + s) * 32 + sp;
                if (hf == 0) seqh[off] = hb;
                else         seql[off] = lb;
                r0a = r2a; r0b = r2b; r1a = r3a; r1b = r3b;
                if (tl < CH - 1) {
                    r2a = pbase[(2 * tl + 4) * 4 + h2o]; r2b = pbase[(2 * tl + 4) * 4 + h2o + 1];
                    r3a = pbase[(2 * tl + 5) * 4 + h2o]; r3b = pbase[(2 * tl + 5) * 4 + h2o + 1];
                }
            }
        }
    }
}

// ============ K2: MFMA LSTM, 16 samples/wave (R15 + cvt_pk repack) =========
__global__ __launch_bounds__(64, 1) void lstm_mfma_kernel(
    const unsigned short* __restrict__ seqh, const unsigned short* __restrict__ seql,
    const float* __restrict__ wih, const float* __restrict__ whh,
    const float* __restrict__ bih, const float* __restrict__ bhh,
    float* __restrict__ state, float* __restrict__ feats,
    int t0, int Tseg)
{
    const int s0   = blockIdx.x * 16;
    const int br   = blockIdx.y;
    const int lane = threadIdx.x;
    const int c    = lane & 15;   // sample col
    const int q    = lane >> 4;

    // bias in registers (D layout: gate = 16n + 4q + r)
    f32x4 bias[8];
    #pragma unroll
    for (int n = 0; n < 8; ++n)
        #pragma unroll
        for (int r = 0; r < 4; ++r) {
            int g = 16 * n + 4 * q + r;
            bias[n][r] = bih[br * 128 + g] + bhh[br * 128 + g];
        }

    // weight A-frags: row = c (gate 16n+c), k elems {4q+j} u {16+4q+j}
    b16x8 wihhi[8], wihlo[8], whhhi[8], whhlo[8];
    #pragma unroll
    for (int n = 0; n < 8; ++n) {
        const int gr = 16 * n + c;
        const float* pi = wih + (size_t)br * 4096 + (size_t)gr * 32;
        const float* ph = whh + (size_t)br * 4096 + (size_t)gr * 32;
        v4f ia = *(const v4f*)(pi + 4 * q);
        v4f ib = *(const v4f*)(pi + 16 + 4 * q);
        v4f ha = *(const v4f*)(ph + 4 * q);
        v4f hb = *(const v4f*)(ph + 16 + 4 * q);
        #pragma unroll
        for (int j = 0; j < 4; ++j) {
            __bf16 t;
            t = (__bf16)ia[j]; wihhi[n][j]     = t; wihlo[n][j]     = (__bf16)(ia[j] - (float)t);
            t = (__bf16)ib[j]; wihhi[n][4 + j] = t; wihlo[n][4 + j] = (__bf16)(ib[j] - (float)t);
            t = (__bf16)ha[j]; whhhi[n][j]     = t; whhlo[n][j]     = (__bf16)(ha[j] - (float)t);
            t = (__bf16)hb[j]; whhhi[n][4 + j] = t; whhlo[n][4 + j] = (__bf16)(hb[j] - (float)t);
        }
    }

    // state: init or restore
    b16x8 bhh_f, bhl_f;
    float cst[2][4];
    if (t0 == 0) {
        #pragma unroll
        for (int j = 0; j < 8; ++j) { bhh_f[j] = (__bf16)0.f; bhl_f[j] = (__bf16)0.f; }
        #pragma unroll
        for (int hh = 0; hh < 2; ++hh)
            #pragma unroll
            for (int r = 0; r < 4; ++r) cst[hh][r] = 0.f;
    } else {
        const float* st = state + (((size_t)br * BATCH + s0 + c) * 2) * 32;
        #pragma unroll
        for (int hh = 0; hh < 2; ++hh)
            #pragma unroll
            for (int r = 0; r < 4; ++r) {
                int u = 16 * hh + 4 * q + r;
                float hv = st[u];
                __bf16 hb2 = (__bf16)hv;
                bhh_f[hh * 4 + r] = hb2;
                bhl_f[hh * 4 + r] = (__bf16)(hv - (float)hb2);
                cst[hh][r] = st[32 + u];
            }
    }

    // x pointers (bump per step)
    const size_t xbase = ((size_t)br * Tseg * 2048 + s0 + c) * 32 + (size_t)q * 8;
    const size_t xstep = 2048 * 32;
    const unsigned short* ph = seqh + xbase;
    const unsigned short* pl = seql + xbase;

    // prologue: xacc = bias + Wih*x(0); prefetch x(1)
    f32x4 xacc[8];
    b16x8 nh1, nl1;
    {
        b16x8 x0h = *(const b16x8*)ph;
        b16x8 x0l = *(const b16x8*)pl;
        #pragma unroll
        for (int n = 0; n < 8; ++n) {
            xacc[n] = __builtin_amdgcn_mfma_f32_16x16x32_bf16(wihhi[n], x0h, bias[n], 0, 0, 0);
            xacc[n] = __builtin_amdgcn_mfma_f32_16x16x32_bf16(wihhi[n], x0l, xacc[n], 0, 0, 0);
            xacc[n] = __builtin_amdgcn_mfma_f32_16x16x32_bf16(wihlo[n], x0h, xacc[n], 0, 0, 0);
        }
        nh1 = *(const b16x8*)(ph + xstep);
        nl1 = *(const b16x8*)(pl + xstep);
    }

    #pragma unroll 1
    for (int t = 0; t < Tseg; ++t) {
        const bool last = (t0 + t == TSTEPS - 1);
        b16x8 nh2, nl2;
        if (t + 2 < Tseg) {
            nh2 = *(const b16x8*)(ph + (size_t)(t + 2) * xstep);
            nl2 = *(const b16x8*)(pl + (size_t)(t + 2) * xstep);
        }

        // h-part: 3 chained MFMAs per n on pipelined xacc
        #pragma unroll
        for (int n = 0; n < 8; ++n) {
            xacc[n] = __builtin_amdgcn_mfma_f32_16x16x32_bf16(whhhi[n], bhh_f, xacc[n], 0, 0, 0);
            xacc[n] = __builtin_amdgcn_mfma_f32_16x16x32_bf16(whhhi[n], bhl_f, xacc[n], 0, 0, 0);
            xacc[n] = __builtin_amdgcn_mfma_f32_16x16x32_bf16(whhlo[n], bhh_f, xacc[n], 0, 0, 0);
        }

        // activations + cell update -> hv[8] (elem order hh*4+r)
        float hv[8];
        #pragma unroll
        for (int hh = 0; hh < 2; ++hh) {
            #pragma unroll
            for (int r = 0; r < 4; ++r) {
                float gi = xacc[0 + hh][r];
                float gf = xacc[2 + hh][r];
                float gg = xacc[4 + hh][r];
                float go = xacc[6 + hh][r];
                float si = sigf(gi);
                float sf = sigf(gf);
                float tg = tanhfast(gg);
                float so = sigf(go);
                float cc = fmaf(sf, cst[hh][r], si * tg);
                cst[hh][r] = cc;
                hv[hh * 4 + r] = so * tanhfast(cc);
            }
        }

        // repack h -> bf16 hi/lo via v_cvt_pk_bf16_f32 (2 f32 -> 1 dword)
        {
            u32x4 hd, ld;
            #pragma unroll
            for (int p = 0; p < 4; ++p) {
                float a = hv[2 * p], b = hv[2 * p + 1];
                unsigned d = cvtpk_bf16(a, b);
                float fa = __uint_as_float(d << 16);
                float fb = __uint_as_float(d & 0xFFFF0000u);
                ld[p] = cvtpk_bf16(a - fa, b - fb);
                hd[p] = d;
            }
            bhh_f = __builtin_bit_cast(b16x8, hd);
            bhl_f = __builtin_bit_cast(b16x8, ld);
        }

        if (last) {
            float* fp = feats + ((size_t)br * BATCH + s0 + c) * 32 + 4 * q;
            #pragma unroll
            for (int r = 0; r < 4; ++r) { fp[r] = hv[r]; fp[16 + r] = hv[4 + r]; }
        }

        // xacc for step t+1 from x(t+1) (off the h-critical-path)
        if (t < Tseg - 1) {
            #pragma unroll
            for (int n = 0; n < 8; ++n) {
                xacc[n] = __builtin_amdgcn_mfma_f32_16x16x32_bf16(wihhi[n], nh1, bias[n], 0, 0, 0);
                xacc[n] = __builtin_amdgcn_mfma_f32_16x16x32_bf16(wihhi[n], nl1, xacc[n], 0, 0, 0);
                xacc[n] = __builtin_amdgcn_mfma_f32_16x16x32_bf16(wihlo[n], nh1, xacc[n], 0, 0, 0);
            }
            nh1 = nh2; nl1 = nl2;
        }
    }

    // save state for next segment
    if (t0 + Tseg < TSTEPS) {
        float* st = state + (((size_t)br * BATCH + s0 + c) * 2) * 32;
        #pragma unroll
        for (int hh = 0; hh < 2; ++hh)
            #pragma unroll
            for (int r = 0; r < 4; ++r) {
                int u = 16 * hh + 4 * q + r;
                st[u]      = (float)bhh_f[hh * 4 + r] + (float)bhl_f[hh * 4 + r];
                st[32 + u] = cst[hh][r];
            }
    }
}

// ============ fallback: R7 monolithic branch kernel ========================
__global__ __launch_bounds__(64, 2) void branch_fallback(
    const float* __restrict__ x0, const float* __restrict__ x1,
    const float* __restrict__ x2, const float* __restrict__ x3,
    const float* __restrict__ c1w, const float* __restrict__ c1b,
    const float* __restrict__ c2w, const float* __restrict__ c2b,
    const float* __restrict__ wih, const float* __restrict__ whh,
    const float* __restrict__ bih, const float* __restrict__ bhh,
    float* __restrict__ feats)
{
    const int s    = blockIdx.x;
    const int br   = blockIdx.y;
    const int lane = threadIdx.x;
    const float* xg = (br == 0) ? x0 : (br == 1) ? x1 : (br == 2) ? x2 : x3;

    __shared__ float xs_c[70];
    __shared__ float p1buf[34][16];
    __shared__ float seqb[CH][32];
    __shared__ float hb[2][32];

    const int ci = lane & 15;
    const int co = lane & 31;
    const int hf = lane >> 5;

    const float bs0 = bih[br * 128 + lane]      + bhh[br * 128 + lane];
    const float bs1 = bih[br * 128 + lane + 64] + bhh[br * 128 + lane + 64];

    if (lane < 32) hb[0][lane] = 0.f;
    float c_state = 0.f;

    #pragma unroll 1
    for (int chk = 0; chk < NCHUNK; ++chk) {
        const int tc0 = chk * CH;
        {
            int g = 4 * tc0 - 3 + lane;
            xs_c[lane] = ((unsigned)g < (unsigned)LSIG) ? xg[(size_t)s * LSIG + g] : 0.f;
            if (lane < 6) {
                int g2 = 4 * tc0 + 61 + lane;
                xs_c[64 + lane] = ((unsigned)g2 < (unsigned)LSIG) ? xg[(size_t)s * LSIG + g2] : 0.f;
            }
        }
        const float* pc1 = c1w + br * 48 + ci * 3;  asm volatile("" : "+v"(pc1));
        const float w10 = pc1[0], w11 = pc1[1], w12 = pc1[2];
        const float* pb1 = c1b + br * 16 + ci;      asm volatile("" : "+v"(pb1));
        const float b1v = pb1[0];
        const float* pc2 = c2w + br * 1536 + co * 48 + hf * 24;
        asm volatile("" : "+v"(pc2));
        float wt[24];
        #pragma unroll
        for (int i = 0; i < 6; ++i) ((v4f*)wt)[i] = ((const v4f*)pc2)[i];
        v4f w2p[3][2];
        #pragma unroll
        for (int k = 0; k < 3; ++k)
            #pragma unroll
            for (int h2 = 0; h2 < 2; ++h2)
                w2p[k][h2] = (v4f){ wt[(h2 * 4 + 0) * 3 + k], wt[(h2 * 4 + 1) * 3 + k],
                                    wt[(h2 * 4 + 2) * 3 + k], wt[(h2 * 4 + 3) * 3 + k] };
        const float* pb2 = c2b + br * 32 + co;      asm volatile("" : "+v"(pb2));
        const float b2v = pb2[0];
        __syncthreads();
        #pragma unroll 1
        for (int it = 0; it < 9; ++it) {
            int idx = it * 64 + lane;
            if (idx < 34 * 16) {
                int pl = idx >> 4;
                float xa = xs_c[2 * pl + 0], xb = xs_c[2 * pl + 1];
                float xc = xs_c[2 * pl + 2], xd = xs_c[2 * pl + 3];
                float a0 = fmaf(xc, w12, fmaf(xb, w11, fmaf(xa, w10, b1v)));
                float a1 = fmaf(xd, w12, fmaf(xc, w11, fmaf(xb, w10, b1v)));
                float v = fmaxf(fmaxf(a0, a1), 0.f);
                int p1g = 2 * tc0 - 1 + pl;
                v = ((unsigned)p1g < (unsigned)(LSIG / 2)) ? v : 0.f;
                p1buf[pl][idx & 15] = v;
            }
        }
        __syncthreads();
        {
            const v4f* pbase = (const v4f*)&p1buf[0][0];
            const int h2o = hf * 2;
            v4f r0a = pbase[0 * 4 + h2o], r0b = pbase[0 * 4 + h2o + 1];
            v4f r1a = pbase[1 * 4 + h2o], r1b = pbase[1 * 4 + h2o + 1];
            v4f r2a = pbase[2 * 4 + h2o], r2b = pbase[2 * 4 + h2o + 1];
            v4f r3a = pbase[3 * 4 + h2o], r3b = pbase[3 * 4 + h2o + 1];
            #pragma unroll 1
            for (int tl = 0; tl < CH; ++tl) {
                v2f aA = {0.f, 0.f}, aB = {0.f, 0.f};
                PKFMA(aA, r0a.xy, w2p[0][0].xy); PKFMA(aA, r0a.zw, w2p[0][0].zw);
                PKFMA(aA, r0b.xy, w2p[0][1].xy); PKFMA(aA, r0b.zw, w2p[0][1].zw);
                PKFMA(aA, r1a.xy, w2p[1][0].xy); PKFMA(aA, r1a.zw, w2p[1][0].zw);
                PKFMA(aA, r1b.xy, w2p[1][1].xy); PKFMA(aA, r1b.zw, w2p[1][1].zw);
                PKFMA(aA, r2a.xy, w2p[2][0].xy); PKFMA(aA, r2a.zw, w2p[2][0].zw);
                PKFMA(aA, r2b.xy, w2p[2][1].xy); PKFMA(aA, r2b.zw, w2p[2][1].zw);
                PKFMA(aB, r1a.xy, w2p[0][0].xy); PKFMA(aB, r1a.zw, w2p[0][0].zw);
                PKFMA(aB, r1b.xy, w2p[0][1].xy); PKFMA(aB, r1b.zw, w2p[0][1].zw);
                PKFMA(aB, r2a.xy, w2p[1][0].xy); PKFMA(aB, r2a.zw, w2p[1][0].zw);
                PKFMA(aB, r2b.xy, w2p[1][1].xy); PKFMA(aB, r2b.zw, w2p[1][1].zw);
                PKFMA(aB, r3a.xy, w2p[2][0].xy); PKFMA(aB, r3a.zw, w2p[2][0].zw);
                PKFMA(aB, r3b.xy, w2p[2][1].xy); PKFMA(aB, r3b.zw, w2p[2][1].zw);
                float sA = aA.x + aA.y, sB = aB.x + aB.y;
                sA += __shfl_xor(sA, 32);
                sB += __shfl_xor(sB, 32);
                if (hf == 0)
                    seqb[tl][co] = fmaxf(fmaxf(sA, sB) + b2v, 0.f);
                r0a = r2a; r0b = r2b; r1a = r3a; r1b = r3b;
                if (tl < CH - 1) {
                    r2a = pbase[(2 * tl + 4) * 4 + h2o]; r2b = pbase[(2 * tl + 4) * 4 + h2o + 1];
                    r3a = pbase[(2 * tl + 5) * 4 + h2o]; r3b = pbase[(2 * tl + 5) * 4 + h2o + 1];
                }
            }
        }
        __syncthreads();
        float gpx0[CH], gpx1[CH];
        {
            const float* pwi = wih + (size_t)br * 4096 + (size_t)lane * 32;
            asm volatile("" : "+v"(pwi));
            v4f wiA[8], wiB[8];
            #pragma unroll
            for (int j = 0; j < 8; ++j) {
                wiA[j] = ((const v4f*)pwi)[j];
                wiB[j] = ((const v4f*)(pwi + 64 * 32))[j];
            }
            #pragma unroll
            for (int tl = 0; tl < CH; ++tl) {
                const v4f* xq = (const v4f*)&seqb[tl][0];
                v2f aA = {0.f, 0.f}, aB = {0.f, 0.f};
                #pragma unroll
                for (int j = 0; j < 8; ++j) {
                    v4f xv = xq[j];
                    PKFMA(aA, xv.xy, wiA[j].xy); PKFMA(aA, xv.zw, wiA[j].zw);
                    PKFMA(aB, xv.xy, wiB[j].xy); PKFMA(aB, xv.zw, wiB[j].zw);
                }
                gpx0[tl] = aA.x + aA.y;
                gpx1[tl] = aB.x + aB.y;
            }
        }
        {
            const float* pwh = whh + (size_t)br * 4096 + (size_t)lane * 32;
            asm volatile("" : "+v"(pwh));
            v4f whA[8], whB[8];
            #pragma unroll
            for (int j = 0; j < 8; ++j) {
                whA[j] = ((const v4f*)pwh)[j];
                whB[j] = ((const v4f*)(pwh + 64 * 32))[j];
            }
            #pragma unroll
            for (int tl = 0; tl < CH; ++tl) {
                __syncthreads();
                const int p = (tc0 + tl) & 1;
                const v4f* hq = (const v4f*)&hb[p][0];
                v2f aA = {0.f, 0.f}, aB = {0.f, 0.f};
                #pragma unroll
                for (int j = 0; j < 8; ++j) {
                    v4f hv = hq[j];
                    PKFMA(aA, hv.xy, whA[j].xy); PKFMA(aA, hv.zw, whA[j].zw);
                    PKFMA(aB, hv.xy, whB[j].xy); PKFMA(aB, hv.zw, whB[j].zw);
                }
                float g0 = bs0 + gpx0[tl] + aA.x + aA.y;
                float g1 = bs1 + gpx1[tl] + aB.x + aB.y;
                float a0 = sigf(g0);
                float earg = (lane < 32) ? 2.f * g1 : -g1;
                float e1 = __expf(fminf(earg, 80.f));
                float num = (lane < 32) ? e1 - 1.f : 1.f;
                float a1 = __fdividef(num, e1 + 1.f);
                float fa = __shfl_xor(a0, 32);
                float oa = __shfl_xor(a1, 32);
                if (lane < 32) {
                    c_state = fmaf(fa, c_state, a0 * a1);
                    hb[p ^ 1][lane] = oa * tanhfast(c_state);
                }
            }
        }
    }
    __syncthreads();
    if (lane < 32)
        feats[((size_t)br * BATCH + s) * 32 + lane] = hb[0][lane];
}

// ---------------- tail: bottleneck + 8-qubit statevector + classifier -------

__device__ __forceinline__ void apply1q(float2* psi, int lane, int q,
                                        float2 g00, float2 g01,
                                        float2 g10, float2 g11)
{
    const int shift = 7 - q;
    const int right = 1 << shift;
    #pragma unroll
    for (int pp = 0; pp < 2; ++pp) {
        int p  = lane + 64 * pp;
        int l  = p >> shift;
        int r  = p & (right - 1);
        int i0 = (l << (shift + 1)) + r;
        int i1 = i0 + right;
        float2 a = psi[i0], b = psi[i1];
        float2 n0 = make_float2(g00.x * a.x - g00.y * a.y + g01.x * b.x - g01.y * b.y,
                                g00.x * a.y + g00.y * a.x + g01.x * b.y + g01.y * b.x);
        float2 n1 = make_float2(g10.x * a.x - g10.y * a.y + g11.x * b.x - g11.y * b.y,
                                g10.x * a.y + g10.y * a.x + g11.x * b.y + g11.y * b.x);
        psi[i0] = n0;
        psi[i1] = n1;
    }
    __syncthreads();
}

__global__ __launch_bounds__(64) void tail_kernel(
    const float* __restrict__ feats, const float* __restrict__ bw,
    const float* __restrict__ bb, const float* __restrict__ qw,
    const float* __restrict__ cw, const float* __restrict__ cb,
    float* __restrict__ out)
{
    const int s    = blockIdx.x;
    const int lane = threadIdx.x;

    __shared__ float comb[128];
    __shared__ float2 psi[256];
    __shared__ float ang[8];

    comb[lane]      = feats[(size_t)(lane >> 5) * (BATCH * 32) + (size_t)s * 32 + (lane & 31)];
    comb[lane + 64] = feats[(size_t)((lane + 64) >> 5) * (BATCH * 32) + (size_t)s * 32 + (lane & 31)];
    __syncthreads();

    {
        int q = lane >> 3, k0 = lane & 7;
        float p = 0.f;
        #pragma unroll
        for (int i = 0; i < 16; ++i) {
            int k = k0 + 8 * i;
            p = fmaf(comb[k], bw[q * 128 + k], p);
        }
        p += __shfl_xor(p, 4);
        p += __shfl_xor(p, 2);
        p += __shfl_xor(p, 1);
        if (k0 == 0) ang[q] = tanhf(p + bb[q]);
    }
    #pragma unroll
    for (int r = 0; r < 4; ++r) {
        int idx = lane + 64 * r;
        psi[idx] = make_float2(idx == 0 ? 1.f : 0.f, 0.f);
    }
    __syncthreads();

    const float PI_F = 3.14159265358979323846f;

    for (int q = 0; q < 8; ++q) {
        float half = ang[q] * PI_F * 0.5f;
        float cv = cosf(half), sv = sinf(half);
        apply1q(psi, lane, q,
                make_float2(cv, 0.f), make_float2(0.f, -sv),
                make_float2(0.f, -sv), make_float2(cv, 0.f));
    }

    for (int l = 0; l < 3; ++l) {
        for (int q = 0; q < 8; ++q) {
            float phi = qw[(l * 8 + q) * 3 + 0];
            float th  = qw[(l * 8 + q) * 3 + 1];
            float om  = qw[(l * 8 + q) * 3 + 2];
            float ct = cosf(0.5f * th), st = sinf(0.5f * th);
            float A = 0.5f * (phi + om), D = 0.5f * (phi - om);
            float cA = cosf(A), sA = sinf(A), cD = cosf(D), sD = sinf(D);
            apply1q(psi, lane, q,
                    make_float2(ct * cA, -ct * sA), make_float2(-st * cD, -st * sD),
                    make_float2(st * cD, -st * sD), make_float2(ct * cA,  ct * sA));
        }
        int stride = l + 1;
        for (int q = 0; q + stride < 8; ++q) {
            int cbit = 1 << (7 - q);
            int tbit = 1 << (7 - (q + stride));
            #pragma unroll
            for (int r = 0; r < 4; ++r) {
                int idx = lane + 64 * r;
                if ((idx & cbit) && !(idx & tbit)) {
                    int j = idx | tbit;
                    float2 tmp = psi[idx];
                    psi[idx] = psi[j];
                    psi[j] = tmp;
                }
            }
            __syncthreads();
        }
    }

    float z[8];
    #pragma unroll
    for (int q = 0; q < 8; ++q) z[q] = 0.f;
    #pragma unroll
    for (int r = 0; r < 4; ++r) {
        int idx = lane + 64 * r;
        float2 a = psi[idx];
        float pr = a.x * a.x + a.y * a.y;
        #pragma unroll
        for (int q = 0; q < 8; ++q)
            z[q] += (idx & (1 << (7 - q))) ? -pr : pr;
    }
    #pragma unroll
    for (int q = 0; q < 8; ++q) {
        #pragma unroll
        for (int off = 32; off; off >>= 1) z[q] += __shfl_xor(z[q], off);
    }
    if (lane == 0) {
        #pragma unroll
        for (int c = 0; c < 3; ++c) {
            float acc = cb[c];
            #pragma unroll
            for (int q = 0; q < 8; ++q) acc = fmaf(z[q], cw[c * 8 + q], acc);
            out[s * 3 + c] = acc;
        }
    }
}

extern "C" void kernel_launch(void* const* d_in, const int* in_sizes, int n_in,
                              void* d_out, int out_size, void* d_ws, size_t ws_size,
                              hipStream_t stream)
{
    (void)in_sizes; (void)n_in; (void)out_size;
    const float* x0  = (const float*)d_in[0];
    const float* x1  = (const float*)d_in[1];
    const float* x2  = (const float*)d_in[2];
    const float* x3  = (const float*)d_in[3];
    const float* c1w = (const float*)d_in[4];
    const float* c1b = (const float*)d_in[5];
    const float* c2w = (const float*)d_in[6];
    const float* c2b = (const float*)d_in[7];
    const float* wih = (const float*)d_in[8];
    const float* whh = (const float*)d_in[9];
    const float* bih = (const float*)d_in[10];
    const float* bhh = (const float*)d_in[11];
    const float* bw  = (const float*)d_in[12];
    const float* bb  = (const float*)d_in[13];
    const float* qw  = (const float*)d_in[14];
    const float* cw  = (const float*)d_in[15];
    const float* cb  = (const float*)d_in[16];

    const size_t state_b = 4ULL * BATCH * 64ULL * 4ULL;       // 2 MB
    const size_t feats_b = 4ULL * BATCH * 32ULL * 4ULL;       // 1 MB
    const size_t per_t   = 4ULL * 2048ULL * 32ULL * 4ULL;     // 1 MB/step (hi+lo)

    int Tseg = 0;
    for (int cand = 512; cand >= 32; cand >>= 1) {
        if ((size_t)cand * per_t + state_b + feats_b <= ws_size) { Tseg = cand; break; }
    }

    if (Tseg > 0) {
        size_t seg_elems = (size_t)Tseg * 4ULL * 2048ULL * 32ULL;
        unsigned short* seqh = (unsigned short*)d_ws;
        unsigned short* seql = seqh + seg_elems;
        float* state = (float*)((char*)d_ws + 2ULL * seg_elems * 2ULL);
        float* feats = (float*)((char*)state + state_b);

        const int slots = Tseg / CH;
        const int nck   = (slots >= 4) ? 4 : slots;

        for (int t0 = 0; t0 < TSTEPS; t0 += Tseg) {
            frontend_kernel<<<dim3(BATCH, 4 * (slots / nck)), 64, 0, stream>>>(
                x0, x1, x2, x3, c1w, c1b, c2w, c2b, seqh, seql, t0, Tseg, nck);
            lstm_mfma_kernel<<<dim3(BATCH / 16, 4), 64, 0, stream>>>(
                seqh, seql, wih, whh, bih, bhh, state, feats, t0, Tseg);
        }
        tail_kernel<<<BATCH, 64, 0, stream>>>(
            feats, bw, bb, qw, cw, cb, (float*)d_out);
    } else {
        float* feats = (float*)d_ws;
        branch_fallback<<<dim3(BATCH, 4), 64, 0, stream>>>(
            x0, x1, x2, x3, c1w, c1b, c2w, c2b, wih, whh, bih, bhh, feats);
        tail_kernel<<<BATCH, 64, 0, stream>>>(
            feats, bw, bb, qw, cw, cb, (float*)d_out);
    }
}

// Round 17
// 1467.486 us; speedup vs baseline: 1.7193x; 1.0202x over previous
//
#include <hip/hip_runtime.h>
#include <hip/hip_bf16.h>

#define BATCH 2048
#define LSIG 2048
#define TSTEPS 512
#define CH 16
#define NCHUNK (TSTEPS / CH)

typedef float v2f __attribute__((ext_vector_type(2)));
typedef float v4f __attribute__((ext_vector_type(4)));
typedef __bf16 b16x8 __attribute__((ext_vector_type(8)));
typedef float f32x4 __attribute__((ext_vector_type(4)));
typedef unsigned int u32x4 __attribute__((ext_vector_type(4)));

#define PKFMA(d, a, b) asm("v_pk_fma_f32 %0, %1, %2, %0" : "+v"(d) : "v"(a), "v"(b))
#define PIN(x) asm volatile("" : "+v"(x))

__device__ __forceinline__ float sigf(float x) {
    return __fdividef(1.f, 1.f + __expf(-x));
}
__device__ __forceinline__ float tanhfast(float x) {
    return 1.f - __fdividef(2.f, __expf(2.f * x) + 1.f);
}
__device__ __forceinline__ unsigned short bf16rne(float f) {
    unsigned u = __float_as_uint(f);
    return (unsigned short)((u + 0x7FFFu + ((u >> 16) & 1u)) >> 16);
}
__device__ __forceinline__ unsigned cvtpk_bf16(float a, float b) {
    unsigned d;
    asm("v_cvt_pk_bf16_f32 %0, %1, %2" : "=v"(d) : "v"(a), "v"(b));
    return d;
}
__device__ __forceinline__ int swz(int co) {
    return (co < 16) ? ((co >> 2) * 8 + (co & 3))
                     : (((co >> 2) - 4) * 8 + 4 + (co & 3));
}

// ============ K1: conv front-end, NCK chunks per block -> seq planes =======
__global__ __launch_bounds__(64) void frontend_kernel(
    const float* __restrict__ x0, const float* __restrict__ x1,
    const float* __restrict__ x2, const float* __restrict__ x3,
    const float* __restrict__ c1w, const float* __restrict__ c1b,
    const float* __restrict__ c2w, const float* __restrict__ c2b,
    unsigned short* __restrict__ seqh, unsigned short* __restrict__ seql,
    int t0, int Tseg, int nck)
{
    const int s    = blockIdx.x;
    const int br   = blockIdx.y & 3;
    const int cko  = blockIdx.y >> 2;
    const int lane = threadIdx.x;
    const float* xg = (br == 0) ? x0 : (br == 1) ? x1 : (br == 2) ? x2 : x3;

    __shared__ float xs_c[70];
    __shared__ float p1buf[34][16];

    const int ci = lane & 15;
    const int co = lane & 31;
    const int hf = lane >> 5;
    const int sp = swz(co);

    const float w10 = c1w[br * 48 + ci * 3 + 0];
    const float w11 = c1w[br * 48 + ci * 3 + 1];
    const float w12 = c1w[br * 48 + ci * 3 + 2];
    const float b1v = c1b[br * 16 + ci];

    float wt[24];
    {
        const v4f* p = (const v4f*)(c2w + br * 1536 + co * 48 + hf * 24);
        #pragma unroll
        for (int i = 0; i < 6; ++i) ((v4f*)wt)[i] = p[i];
    }
    v4f w2p[3][2];
    #pragma unroll
    for (int k = 0; k < 3; ++k)
        #pragma unroll
        for (int h2 = 0; h2 < 2; ++h2)
            w2p[k][h2] = (v4f){ wt[(h2 * 4 + 0) * 3 + k], wt[(h2 * 4 + 1) * 3 + k],
                                wt[(h2 * 4 + 2) * 3 + k], wt[(h2 * 4 + 3) * 3 + k] };
    const float b2v = c2b[br * 32 + co];

    #pragma unroll 1
    for (int ic = 0; ic < nck; ++ic) {
        const int ck  = cko * nck + ic;
        const int tc0 = t0 + ck * CH;
        const int lt0 = ck * CH;

        __syncthreads();
        {
            int g = 4 * tc0 - 3 + lane;
            xs_c[lane] = ((unsigned)g < (unsigned)LSIG) ? xg[(size_t)s * LSIG + g] : 0.f;
            if (lane < 6) {
                int g2 = 4 * tc0 + 61 + lane;
                xs_c[64 + lane] = ((unsigned)g2 < (unsigned)LSIG) ? xg[(size_t)s * LSIG + g2] : 0.f;
            }
        }
        __syncthreads();

        #pragma unroll 1
        for (int it = 0; it < 9; ++it) {
            int idx = it * 64 + lane;
            if (idx < 34 * 16) {
                int pl = idx >> 4;
                float xa = xs_c[2 * pl + 0], xb = xs_c[2 * pl + 1];
                float xc = xs_c[2 * pl + 2], xd = xs_c[2 * pl + 3];
                float a0 = fmaf(xc, w12, fmaf(xb, w11, fmaf(xa, w10, b1v)));
                float a1 = fmaf(xd, w12, fmaf(xc, w11, fmaf(xb, w10, b1v)));
                float v = fmaxf(fmaxf(a0, a1), 0.f);
                int p1g = 2 * tc0 - 1 + pl;
                v = ((unsigned)p1g < (unsigned)(LSIG / 2)) ? v : 0.f;
                p1buf[pl][idx & 15] = v;
            }
        }
        __syncthreads();

        {
            const v4f* pbase = (const v4f*)&p1buf[0][0];
            const int h2o = hf * 2;
            v4f r0a = pbase[0 * 4 + h2o], r0b = pbase[0 * 4 + h2o + 1];
            v4f r1a = pbase[1 * 4 + h2o], r1b = pbase[1 * 4 + h2o + 1];
            v4f r2a = pbase[2 * 4 + h2o], r2b = pbase[2 * 4 + h2o + 1];
            v4f r3a = pbase[3 * 4 + h2o], r3b = pbase[3 * 4 + h2o + 1];
            #pragma unroll 1
            for (int tl = 0; tl < CH; ++tl) {
                v2f aA = {0.f, 0.f}, aB = {0.f, 0.f};
                PKFMA(aA, r0a.xy, w2p[0][0].xy); PKFMA(aA, r0a.zw, w2p[0][0].zw);
                PKFMA(aA, r0b.xy, w2p[0][1].xy); PKFMA(aA, r0b.zw, w2p[0][1].zw);
                PKFMA(aA, r1a.xy, w2p[1][0].xy); PKFMA(aA, r1a.zw, w2p[1][0].zw);
                PKFMA(aA, r1b.xy, w2p[1][1].xy); PKFMA(aA, r1b.zw, w2p[1][1].zw);
                PKFMA(aA, r2a.xy, w2p[2][0].xy); PKFMA(aA, r2a.zw, w2p[2][0].zw);
                PKFMA(aA, r2b.xy, w2p[2][1].xy); PKFMA(aA, r2b.zw, w2p[2][1].zw);
                PKFMA(aB, r1a.xy, w2p[0][0].xy); PKFMA(aB, r1a.zw, w2p[0][0].zw);
                PKFMA(aB, r1b.xy, w2p[0][1].xy); PKFMA(aB, r1b.zw, w2p[0][1].zw);
                PKFMA(aB, r2a.xy, w2p[1][0].xy); PKFMA(aB, r2a.zw, w2p[1][0].zw);
                PKFMA(aB, r2b.xy, w2p[1][1].xy); PKFMA(aB, r2b.zw, w2p[1][1].zw);
                PKFMA(aB, r3a.xy, w2p[2][0].xy); PKFMA(aB, r3a.zw, w2p[2][0].zw);
                PKFMA(aB, r3b.xy, w2p[2][1].xy); PKFMA(aB, r3b.zw, w2p[2][1].zw);
                float sA = aA.x + aA.y, sB = aB.x + aB.y;
                sA += __shfl_xor(sA, 32);
                sB += __shfl_xor(sB, 32);
                float sv = fmaxf(fmaxf(sA, sB) + b2v, 0.f);
                unsigned short hb = bf16rne(sv);
                float hif = __uint_as_float(((unsigned)hb) << 16);
                unsigned short lb = bf16rne(sv - hif);
                size_t off = (((size_t)br * Tseg + (lt0 + tl)) * 2048 + s) * 32 + sp;
                if (hf == 0) seqh[off] = hb;
                else         seql[off] = lb;
                r0a = r2a; r0b = r2b; r1a = r3a; r1b = r3b;
                if (tl < CH - 1) {
                    r2a = pbase[(2 * tl + 4) * 4 + h2o]; r2b = pbase[(2 * tl + 4) * 4 + h2o + 1];
                    r3a = pbase[(2 * tl + 5) * 4 + h2o]; r3b = pbase[(2 * tl + 5) * 4 + h2o + 1];
                }
            }
        }
    }
}

// ============ K2: MFMA LSTM, 16 samples/wave — weights PINNED in VGPRs =====
// R16 anomaly: VGPR_Count=132 << static demand ~230, no scratch => compiler
// re-loads weight frags from global EVERY STEP (L2-hit latency ~200cyc x24
// loads/step => the 4600cyc/step). R17: asm-pin each weight frag after load
// to force residency; bias back to LDS (reg/LDS neutral per R15) for room.
__global__ __launch_bounds__(64, 1) void lstm_mfma_kernel(
    const unsigned short* __restrict__ seqh, const unsigned short* __restrict__ seql,
    const float* __restrict__ wih, const float* __restrict__ whh,
    const float* __restrict__ bih, const float* __restrict__ bhh,
    float* __restrict__ state, float* __restrict__ feats,
    int t0, int Tseg)
{
    const int s0   = blockIdx.x * 16;
    const int br   = blockIdx.y;
    const int lane = threadIdx.x;
    const int c    = lane & 15;   // sample col
    const int q    = lane >> 4;

    __shared__ f32x4 bias_lds[8][64];
    #pragma unroll
    for (int n = 0; n < 8; ++n) {
        f32x4 b;
        #pragma unroll
        for (int r = 0; r < 4; ++r) {
            int g = 16 * n + 4 * q + r;
            b[r] = bih[br * 128 + g] + bhh[br * 128 + g];
        }
        bias_lds[n][lane] = b;
    }
    __syncthreads();

    // weight A-frags: row = c (gate 16n+c), k elems {4q+j} u {16+4q+j}
    b16x8 wihhi[8], wihlo[8], whhhi[8], whhlo[8];
    #pragma unroll
    for (int n = 0; n < 8; ++n) {
        const int gr = 16 * n + c;
        const float* pi = wih + (size_t)br * 4096 + (size_t)gr * 32;
        const float* ph = whh + (size_t)br * 4096 + (size_t)gr * 32;
        v4f ia = *(const v4f*)(pi + 4 * q);
        v4f ib = *(const v4f*)(pi + 16 + 4 * q);
        v4f ha = *(const v4f*)(ph + 4 * q);
        v4f hb = *(const v4f*)(ph + 16 + 4 * q);
        #pragma unroll
        for (int j = 0; j < 4; ++j) {
            __bf16 t;
            t = (__bf16)ia[j]; wihhi[n][j]     = t; wihlo[n][j]     = (__bf16)(ia[j] - (float)t);
            t = (__bf16)ib[j]; wihhi[n][4 + j] = t; wihlo[n][4 + j] = (__bf16)(ib[j] - (float)t);
            t = (__bf16)ha[j]; whhhi[n][j]     = t; whhlo[n][j]     = (__bf16)(ha[j] - (float)t);
            t = (__bf16)hb[j]; whhhi[n][4 + j] = t; whhlo[n][4 + j] = (__bf16)(hb[j] - (float)t);
        }
        // force residency: values must stay in VGPRs (no per-step re-load)
        PIN(wihhi[n]); PIN(wihlo[n]); PIN(whhhi[n]); PIN(whhlo[n]);
    }

    // state: init or restore
    b16x8 bhh_f, bhl_f;
    float cst[2][4];
    if (t0 == 0) {
        #pragma unroll
        for (int j = 0; j < 8; ++j) { bhh_f[j] = (__bf16)0.f; bhl_f[j] = (__bf16)0.f; }
        #pragma unroll
        for (int hh = 0; hh < 2; ++hh)
            #pragma unroll
            for (int r = 0; r < 4; ++r) cst[hh][r] = 0.f;
    } else {
        const float* st = state + (((size_t)br * BATCH + s0 + c) * 2) * 32;
        #pragma unroll
        for (int hh = 0; hh < 2; ++hh)
            #pragma unroll
            for (int r = 0; r < 4; ++r) {
                int u = 16 * hh + 4 * q + r;
                float hv = st[u];
                __bf16 hb2 = (__bf16)hv;
                bhh_f[hh * 4 + r] = hb2;
                bhl_f[hh * 4 + r] = (__bf16)(hv - (float)hb2);
                cst[hh][r] = st[32 + u];
            }
    }

    // x pointers (bump per step)
    const size_t xbase = ((size_t)br * Tseg * 2048 + s0 + c) * 32 + (size_t)q * 8;
    const size_t xstep = 2048 * 32;
    const unsigned short* ph = seqh + xbase;
    const unsigned short* pl = seql + xbase;

    // prologue: xacc = bias + Wih*x(0); prefetch x(1)
    f32x4 xacc[8];
    b16x8 nh1, nl1;
    {
        b16x8 x0h = *(const b16x8*)ph;
        b16x8 x0l = *(const b16x8*)pl;
        #pragma unroll
        for (int n = 0; n < 8; ++n) {
            xacc[n] = __builtin_amdgcn_mfma_f32_16x16x32_bf16(wihhi[n], x0h, bias_lds[n][lane], 0, 0, 0);
            xacc[n] = __builtin_amdgcn_mfma_f32_16x16x32_bf16(wihhi[n], x0l, xacc[n], 0, 0, 0);
            xacc[n] = __builtin_amdgcn_mfma_f32_16x16x32_bf16(wihlo[n], x0h, xacc[n], 0, 0, 0);
        }
        nh1 = *(const b16x8*)(ph + xstep);
        nl1 = *(const b16x8*)(pl + xstep);
    }

    #pragma unroll 1
    for (int t = 0; t < Tseg; ++t) {
        const bool last = (t0 + t == TSTEPS - 1);
        b16x8 nh2, nl2;
        if (t + 2 < Tseg) {
            nh2 = *(const b16x8*)(ph + (size_t)(t + 2) * xstep);
            nl2 = *(const b16x8*)(pl + (size_t)(t + 2) * xstep);
        }

        // h-part: 3 chained MFMAs per n on pipelined xacc
        #pragma unroll
        for (int n = 0; n < 8; ++n) {
            xacc[n] = __builtin_amdgcn_mfma_f32_16x16x32_bf16(whhhi[n], bhh_f, xacc[n], 0, 0, 0);
            xacc[n] = __builtin_amdgcn_mfma_f32_16x16x32_bf16(whhhi[n], bhl_f, xacc[n], 0, 0, 0);
            xacc[n] = __builtin_amdgcn_mfma_f32_16x16x32_bf16(whhlo[n], bhh_f, xacc[n], 0, 0, 0);
        }

        // activations + cell update -> hv[8] (elem order hh*4+r)
        float hv[8];
        #pragma unroll
        for (int hh = 0; hh < 2; ++hh) {
            #pragma unroll
            for (int r = 0; r < 4; ++r) {
                float gi = xacc[0 + hh][r];
                float gf = xacc[2 + hh][r];
                float gg = xacc[4 + hh][r];
                float go = xacc[6 + hh][r];
                float si = sigf(gi);
                float sf = sigf(gf);
                float tg = tanhfast(gg);
                float so = sigf(go);
                float cc = fmaf(sf, cst[hh][r], si * tg);
                cst[hh][r] = cc;
                hv[hh * 4 + r] = so * tanhfast(cc);
            }
        }

        // repack h -> bf16 hi/lo via v_cvt_pk_bf16_f32
        {
            u32x4 hd, ld;
            #pragma unroll
            for (int p = 0; p < 4; ++p) {
                float a = hv[2 * p], b = hv[2 * p + 1];
                unsigned d = cvtpk_bf16(a, b);
                float fa = __uint_as_float(d << 16);
                float fb = __uint_as_float(d & 0xFFFF0000u);
                ld[p] = cvtpk_bf16(a - fa, b - fb);
                hd[p] = d;
            }
            bhh_f = __builtin_bit_cast(b16x8, hd);
            bhl_f = __builtin_bit_cast(b16x8, ld);
        }

        if (last) {
            float* fp = feats + ((size_t)br * BATCH + s0 + c) * 32 + 4 * q;
            #pragma unroll
            for (int r = 0; r < 4; ++r) { fp[r] = hv[r]; fp[16 + r] = hv[4 + r]; }
        }

        // xacc for step t+1 from x(t+1) (off the h-critical-path)
        if (t < Tseg - 1) {
            #pragma unroll
            for (int n = 0; n < 8; ++n) {
                xacc[n] = __builtin_amdgcn_mfma_f32_16x16x32_bf16(wihhi[n], nh1, bias_lds[n][lane], 0, 0, 0);
                xacc[n] = __builtin_amdgcn_mfma_f32_16x16x32_bf16(wihhi[n], nl1, xacc[n], 0, 0, 0);
                xacc[n] = __builtin_amdgcn_mfma_f32_16x16x32_bf16(wihlo[n], nh1, xacc[n], 0, 0, 0);
            }
            nh1 = nh2; nl1 = nl2;
        }
    }

    // save state for next segment
    if (t0 + Tseg < TSTEPS) {
        float* st = state + (((size_t)br * BATCH + s0 + c) * 2) * 32;
        #pragma unroll
        for (int hh = 0; hh < 2; ++hh)
            #pragma unroll
            for (int r = 0; r < 4; ++r) {
                int u = 16 * hh + 4 * q + r;
                st[u]      = (float)bhh_f[hh * 4 + r] + (float)bhl_f[hh * 4 + r];
                st[32 + u] = cst[hh][r];
            }
    }
}

// ============ fallback: R7 monolithic branch kernel ========================
__global__ __launch_bounds__(64, 2) void branch_fallback(
    const float* __restrict__ x0, const float* __restrict__ x1,
    const float* __restrict__ x2, const float* __restrict__ x3,
    const float* __restrict__ c1w, const float* __restrict__ c1b,
    const float* __restrict__ c2w, const float* __restrict__ c2b,
    const float* __restrict__ wih, const float* __restrict__ whh,
    const float* __restrict__ bih, const float* __restrict__ bhh,
    float* __restrict__ feats)
{
    const int s    = blockIdx.x;
    const int br   = blockIdx.y;
    const int lane = threadIdx.x;
    const float* xg = (br == 0) ? x0 : (br == 1) ? x1 : (br == 2) ? x2 : x3;

    __shared__ float xs_c[70];
    __shared__ float p1buf[34][16];
    __shared__ float seqb[CH][32];
    __shared__ float hb[2][32];

    const int ci = lane & 15;
    const int co = lane & 31;
    const int hf = lane >> 5;

    const float bs0 = bih[br * 128 + lane]      + bhh[br * 128 + lane];
    const float bs1 = bih[br * 128 + lane + 64] + bhh[br * 128 + lane + 64];

    if (lane < 32) hb[0][lane] = 0.f;
    float c_state = 0.f;

    #pragma unroll 1
    for (int chk = 0; chk < NCHUNK; ++chk) {
        const int tc0 = chk * CH;
        {
            int g = 4 * tc0 - 3 + lane;
            xs_c[lane] = ((unsigned)g < (unsigned)LSIG) ? xg[(size_t)s * LSIG + g] : 0.f;
            if (lane < 6) {
                int g2 = 4 * tc0 + 61 + lane;
                xs_c[64 + lane] = ((unsigned)g2 < (unsigned)LSIG) ? xg[(size_t)s * LSIG + g2] : 0.f;
            }
        }
        const float* pc1 = c1w + br * 48 + ci * 3;  asm volatile("" : "+v"(pc1));
        const float w10 = pc1[0], w11 = pc1[1], w12 = pc1[2];
        const float* pb1 = c1b + br * 16 + ci;      asm volatile("" : "+v"(pb1));
        const float b1v = pb1[0];
        const float* pc2 = c2w + br * 1536 + co * 48 + hf * 24;
        asm volatile("" : "+v"(pc2));
        float wt[24];
        #pragma unroll
        for (int i = 0; i < 6; ++i) ((v4f*)wt)[i] = ((const v4f*)pc2)[i];
        v4f w2p[3][2];
        #pragma unroll
        for (int k = 0; k < 3; ++k)
            #pragma unroll
            for (int h2 = 0; h2 < 2; ++h2)
                w2p[k][h2] = (v4f){ wt[(h2 * 4 + 0) * 3 + k], wt[(h2 * 4 + 1) * 3 + k],
                                    wt[(h2 * 4 + 2) * 3 + k], wt[(h2 * 4 + 3) * 3 + k] };
        const float* pb2 = c2b + br * 32 + co;      asm volatile("" : "+v"(pb2));
        const float b2v = pb2[0];
        __syncthreads();
        #pragma unroll 1
        for (int it = 0; it < 9; ++it) {
            int idx = it * 64 + lane;
            if (idx < 34 * 16) {
                int pl = idx >> 4;
                float xa = xs_c[2 * pl + 0], xb = xs_c[2 * pl + 1];
                float xc = xs_c[2 * pl + 2], xd = xs_c[2 * pl + 3];
                float a0 = fmaf(xc, w12, fmaf(xb, w11, fmaf(xa, w10, b1v)));
                float a1 = fmaf(xd, w12, fmaf(xc, w11, fmaf(xb, w10, b1v)));
                float v = fmaxf(fmaxf(a0, a1), 0.f);
                int p1g = 2 * tc0 - 1 + pl;
                v = ((unsigned)p1g < (unsigned)(LSIG / 2)) ? v : 0.f;
                p1buf[pl][idx & 15] = v;
            }
        }
        __syncthreads();
        {
            const v4f* pbase = (const v4f*)&p1buf[0][0];
            const int h2o = hf * 2;
            v4f r0a = pbase[0 * 4 + h2o], r0b = pbase[0 * 4 + h2o + 1];
            v4f r1a = pbase[1 * 4 + h2o], r1b = pbase[1 * 4 + h2o + 1];
            v4f r2a = pbase[2 * 4 + h2o], r2b = pbase[2 * 4 + h2o + 1];
            v4f r3a = pbase[3 * 4 + h2o], r3b = pbase[3 * 4 + h2o + 1];
            #pragma unroll 1
            for (int tl = 0; tl < CH; ++tl) {
                v2f aA = {0.f, 0.f}, aB = {0.f, 0.f};
                PKFMA(aA, r0a.xy, w2p[0][0].xy); PKFMA(aA, r0a.zw, w2p[0][0].zw);
                PKFMA(aA, r0b.xy, w2p[0][1].xy); PKFMA(aA, r0b.zw, w2p[0][1].zw);
                PKFMA(aA, r1a.xy, w2p[1][0].xy); PKFMA(aA, r1a.zw, w2p[1][0].zw);
                PKFMA(aA, r1b.xy, w2p[1][1].xy); PKFMA(aA, r1b.zw, w2p[1][1].zw);
                PKFMA(aA, r2a.xy, w2p[2][0].xy); PKFMA(aA, r2a.zw, w2p[2][0].zw);
                PKFMA(aA, r2b.xy, w2p[2][1].xy); PKFMA(aA, r2b.zw, w2p[2][1].zw);
                PKFMA(aB, r1a.xy, w2p[0][0].xy); PKFMA(aB, r1a.zw, w2p[0][0].zw);
                PKFMA(aB, r1b.xy, w2p[0][1].xy); PKFMA(aB, r1b.zw, w2p[0][1].zw);
                PKFMA(aB, r2a.xy, w2p[1][0].xy); PKFMA(aB, r2a.zw, w2p[1][0].zw);
                PKFMA(aB, r2b.xy, w2p[1][1].xy); PKFMA(aB, r2b.zw, w2p[1][1].zw);
                PKFMA(aB, r3a.xy, w2p[2][0].xy); PKFMA(aB, r3a.zw, w2p[2][0].zw);
                PKFMA(aB, r3b.xy, w2p[2][1].xy); PKFMA(aB, r3b.zw, w2p[2][1].zw);
                float sA = aA.x + aA.y, sB = aB.x + aB.y;
                sA += __shfl_xor(sA, 32);
                sB += __shfl_xor(sB, 32);
                if (hf == 0)
                    seqb[tl][co] = fmaxf(fmaxf(sA, sB) + b2v, 0.f);
                r0a = r2a; r0b = r2b; r1a = r3a; r1b = r3b;
                if (tl < CH - 1) {
                    r2a = pbase[(2 * tl + 4) * 4 + h2o]; r2b = pbase[(2 * tl + 4) * 4 + h2o + 1];
                    r3a = pbase[(2 * tl + 5) * 4 + h2o]; r3b = pbase[(2 * tl + 5) * 4 + h2o + 1];
                }
            }
        }
        __syncthreads();
        float gpx0[CH], gpx1[CH];
        {
            const float* pwi = wih + (size_t)br * 4096 + (size_t)lane * 32;
            asm volatile("" : "+v"(pwi));
            v4f wiA[8], wiB[8];
            #pragma unroll
            for (int j = 0; j < 8; ++j) {
                wiA[j] = ((const v4f*)pwi)[j];
                wiB[j] = ((const v4f*)(pwi + 64 * 32))[j];
            }
            #pragma unroll
            for (int tl = 0; tl < CH; ++tl) {
                const v4f* xq = (const v4f*)&seqb[tl][0];
                v2f aA = {0.f, 0.f}, aB = {0.f, 0.f};
                #pragma unroll
                for (int j = 0; j < 8; ++j) {
                    v4f xv = xq[j];
                    PKFMA(aA, xv.xy, wiA[j].xy); PKFMA(aA, xv.zw, wiA[j].zw);
                    PKFMA(aB, xv.xy, wiB[j].xy); PKFMA(aB, xv.zw, wiB[j].zw);
                }
                gpx0[tl] = aA.x + aA.y;
                gpx1[tl] = aB.x + aB.y;
            }
        }
        {
            const float* pwh = whh + (size_t)br * 4096 + (size_t)lane * 32;
            asm volatile("" : "+v"(pwh));
            v4f whA[8], whB[8];
            #pragma unroll
            for (int j = 0; j < 8; ++j) {
                whA[j] = ((const v4f*)pwh)[j];
                whB[j] = ((const v4f*)(pwh + 64 * 32))[j];
            }
            #pragma unroll
            for (int tl = 0; tl < CH; ++tl) {
                __syncthreads();
                const int p = (tc0 + tl) & 1;
                const v4f* hq = (const v4f*)&hb[p][0];
                v2f aA = {0.f, 0.f}, aB = {0.f, 0.f};
                #pragma unroll
                for (int j = 0; j < 8; ++j) {
                    v4f hv = hq[j];
                    PKFMA(aA, hv.xy, whA[j].xy); PKFMA(aA, hv.zw, whA[j].zw);
                    PKFMA(aB, hv.xy, whB[j].xy); PKFMA(aB, hv.zw, whB[j].zw);
                }
                float g0 = bs0 + gpx0[tl] + aA.x + aA.y;
                float g1 = bs1 + gpx1[tl] + aB.x + aB.y;
                float a0 = sigf(g0);
                float earg = (lane < 32) ? 2.f * g1 : -g1;
                float e1 = __expf(fminf(earg, 80.f));
                float num = (lane < 32) ? e1 - 1.f : 1.f;
                float a1 = __fdividef(num, e1 + 1.f);
                float fa = __shfl_xor(a0, 32);
                float oa = __shfl_xor(a1, 32);
                if (lane < 32) {
                    c_state = fmaf(fa, c_state, a0 * a1);
                    hb[p ^ 1][lane] = oa * tanhfast(c_state);
                }
            }
        }
    }
    __syncthreads();
    if (lane < 32)
        feats[((size_t)br * BATCH + s) * 32 + lane] = hb[0][lane];
}

// ---------------- tail: bottleneck + 8-qubit statevector + classifier -------

__device__ __forceinline__ void apply1q(float2* psi, int lane, int q,
                                        float2 g00, float2 g01,
                                        float2 g10, float2 g11)
{
    const int shift = 7 - q;
    const int right = 1 << shift;
    #pragma unroll
    for (int pp = 0; pp < 2; ++pp) {
        int p  = lane + 64 * pp;
        int l  = p >> shift;
        int r  = p & (right - 1);
        int i0 = (l << (shift + 1)) + r;
        int i1 = i0 + right;
        float2 a = psi[i0], b = psi[i1];
        float2 n0 = make_float2(g00.x * a.x - g00.y * a.y + g01.x * b.x - g01.y * b.y,
                                g00.x * a.y + g00.y * a.x + g01.x * b.y + g01.y * b.x);
        float2 n1 = make_float2(g10.x * a.x - g10.y * a.y + g11.x * b.x - g11.y * b.y,
                                g10.x * a.y + g10.y * a.x + g11.x * b.y + g11.y * b.x);
        psi[i0] = n0;
        psi[i1] = n1;
    }
    __syncthreads();
}

__global__ __launch_bounds__(64) void tail_kernel(
    const float* __restrict__ feats, const float* __restrict__ bw,
    const float* __restrict__ bb, const float* __restrict__ qw,
    const float* __restrict__ cw, const float* __restrict__ cb,
    float* __restrict__ out)
{
    const int s    = blockIdx.x;
    const int lane = threadIdx.x;

    __shared__ float comb[128];
    __shared__ float2 psi[256];
    __shared__ float ang[8];

    comb[lane]      = feats[(size_t)(lane >> 5) * (BATCH * 32) + (size_t)s * 32 + (lane & 31)];
    comb[lane + 64] = feats[(size_t)((lane + 64) >> 5) * (BATCH * 32) + (size_t)s * 32 + (lane & 31)];
    __syncthreads();

    {
        int q = lane >> 3, k0 = lane & 7;
        float p = 0.f;
        #pragma unroll
        for (int i = 0; i < 16; ++i) {
            int k = k0 + 8 * i;
            p = fmaf(comb[k], bw[q * 128 + k], p);
        }
        p += __shfl_xor(p, 4);
        p += __shfl_xor(p, 2);
        p += __shfl_xor(p, 1);
        if (k0 == 0) ang[q] = tanhf(p + bb[q]);
    }
    #pragma unroll
    for (int r = 0; r < 4; ++r) {
        int idx = lane + 64 * r;
        psi[idx] = make_float2(idx == 0 ? 1.f : 0.f, 0.f);
    }
    __syncthreads();

    const float PI_F = 3.14159265358979323846f;

    for (int q = 0; q < 8; ++q) {
        float half = ang[q] * PI_F * 0.5f;
        float cv = cosf(half), sv = sinf(half);
        apply1q(psi, lane, q,
                make_float2(cv, 0.f), make_float2(0.f, -sv),
                make_float2(0.f, -sv), make_float2(cv, 0.f));
    }

    for (int l = 0; l < 3; ++l) {
        for (int q = 0; q < 8; ++q) {
            float phi = qw[(l * 8 + q) * 3 + 0];
            float th  = qw[(l * 8 + q) * 3 + 1];
            float om  = qw[(l * 8 + q) * 3 + 2];
            float ct = cosf(0.5f * th), st = sinf(0.5f * th);
            float A = 0.5f * (phi + om), D = 0.5f * (phi - om);
            float cA = cosf(A), sA = sinf(A), cD = cosf(D), sD = sinf(D);
            apply1q(psi, lane, q,
                    make_float2(ct * cA, -ct * sA), make_float2(-st * cD, -st * sD),
                    make_float2(st * cD, -st * sD), make_float2(ct * cA,  ct * sA));
        }
        int stride = l + 1;
        for (int q = 0; q + stride < 8; ++q) {
            int cbit = 1 << (7 - q);
            int tbit = 1 << (7 - (q + stride));
            #pragma unroll
            for (int r = 0; r < 4; ++r) {
                int idx = lane + 64 * r;
                if ((idx & cbit) && !(idx & tbit)) {
                    int j = idx | tbit;
                    float2 tmp = psi[idx];
                    psi[idx] = psi[j];
                    psi[j] = tmp;
                }
            }
            __syncthreads();
        }
    }

    float z[8];
    #pragma unroll
    for (int q = 0; q < 8; ++q) z[q] = 0.f;
    #pragma unroll
    for (int r = 0; r < 4; ++r) {
        int idx = lane + 64 * r;
        float2 a = psi[idx];
        float pr = a.x * a.x + a.y * a.y;
        #pragma unroll
        for (int q = 0; q < 8; ++q)
            z[q] += (idx & (1 << (7 - q))) ? -pr : pr;
    }
    #pragma unroll
    for (int q = 0; q < 8; ++q) {
        #pragma unroll
        for (int off = 32; off; off >>= 1) z[q] += __shfl_xor(z[q], off);
    }
    if (lane == 0) {
        #pragma unroll
        for (int c = 0; c < 3; ++c) {
            float acc = cb[c];
            #pragma unroll
            for (int q = 0; q < 8; ++q) acc = fmaf(z[q], cw[c * 8 + q], acc);
            out[s * 3 + c] = acc;
        }
    }
}

extern "C" void kernel_launch(void* const* d_in, const int* in_sizes, int n_in,
                              void* d_out, int out_size, void* d_ws, size_t ws_size,
                              hipStream_t stream)
{
    (void)in_sizes; (void)n_in; (void)out_size;
    const float* x0  = (const float*)d_in[0];
    const float* x1  = (const float*)d_in[1];
    const float* x2  = (const float*)d_in[2];
    const float* x3  = (const float*)d_in[3];
    const float* c1w = (const float*)d_in[4];
    const float* c1b = (const float*)d_in[5];
    const float* c2w = (const float*)d_in[6];
    const float* c2b = (const float*)d_in[7];
    const float* wih = (const float*)d_in[8];
    const float* whh = (const float*)d_in[9];
    const float* bih = (const float*)d_in[10];
    const float* bhh = (const float*)d_in[11];
    const float* bw  = (const float*)d_in[12];
    const float* bb  = (const float*)d_in[13];
    const float* qw  = (const float*)d_in[14];
    const float* cw  = (const float*)d_in[15];
    const float* cb  = (const float*)d_in[16];

    const size_t state_b = 4ULL * BATCH * 64ULL * 4ULL;       // 2 MB
    const size_t feats_b = 4ULL * BATCH * 32ULL * 4ULL;       // 1 MB
    const size_t per_t   = 4ULL * 2048ULL * 32ULL * 4ULL;     // 1 MB/step (hi+lo)

    int Tseg = 0;
    for (int cand = 512; cand >= 32; cand >>= 1) {
        if ((size_t)cand * per_t + state_b + feats_b <= ws_size) { Tseg = cand; break; }
    }

    if (Tseg > 0) {
        size_t seg_elems = (size_t)Tseg * 4ULL * 2048ULL * 32ULL;
        unsigned short* seqh = (unsigned short*)d_ws;
        unsigned short* seql = seqh + seg_elems;
        float* state = (float*)((char*)d_ws + 2ULL * seg_elems * 2ULL);
        float* feats = (float*)((char*)state + state_b);

        const int slots = Tseg / CH;
        const int nck   = (slots >= 4) ? 4 : slots;

        for (int t0 = 0; t0 < TSTEPS; t0 += Tseg) {
            frontend_kernel<<<dim3(BATCH, 4 * (slots / nck)), 64, 0, stream>>>(
                x0, x1, x2, x3, c1w, c1b, c2w, c2b, seqh, seql, t0, Tseg, nck);
            lstm_mfma_kernel<<<dim3(BATCH / 16, 4), 64, 0, stream>>>(
                seqh, seql, wih, whh, bih, bhh, state, feats, t0, Tseg);
        }
        tail_kernel<<<BATCH, 64, 0, stream>>>(
            feats, bw, bb, qw, cw, cb, (float*)d_out);
    } else {
        float* feats = (float*)d_ws;
        branch_fallback<<<dim3(BATCH, 4), 64, 0, stream>>>(
            x0, x1, x2, x3, c1w, c1b, c2w, c2b, wih, whh, bih, bhh, feats);
        tail_kernel<<<BATCH, 64, 0, stream>>>(
            feats, bw, bb, qw, cw, cb, (float*)d_out);
    }
}

// Round 18
// 1438.162 us; speedup vs baseline: 1.7544x; 1.0204x over previous
//
#include <hip/hip_runtime.h>
#include <hip/hip_bf16.h>

#define BATCH 2048
#define LSIG 2048
#define TSTEPS 512
#define CH 16
#define NCHUNK (TSTEPS / CH)

typedef float v2f __attribute__((ext_vector_type(2)));
typedef float v4f __attribute__((ext_vector_type(4)));
typedef __bf16 b16x8 __attribute__((ext_vector_type(8)));
typedef float f32x4 __attribute__((ext_vector_type(4)));
typedef unsigned int u32x4 __attribute__((ext_vector_type(4)));

#define PKFMA(d, a, b) asm("v_pk_fma_f32 %0, %1, %2, %0" : "+v"(d) : "v"(a), "v"(b))

__device__ __forceinline__ float sigf(float x) {
    return __fdividef(1.f, 1.f + __expf(-x));
}
__device__ __forceinline__ float tanhfast(float x) {
    return 1.f - __fdividef(2.f, __expf(2.f * x) + 1.f);
}
__device__ __forceinline__ unsigned short bf16rne(float f) {
    unsigned u = __float_as_uint(f);
    return (unsigned short)((u + 0x7FFFu + ((u >> 16) & 1u)) >> 16);
}
__device__ __forceinline__ unsigned cvtpk_bf16(float a, float b) {
    unsigned d;
    asm("v_cvt_pk_bf16_f32 %0, %1, %2" : "=v"(d) : "v"(a), "v"(b));
    return d;
}
__device__ __forceinline__ int swz(int co) {
    return (co < 16) ? ((co >> 2) * 8 + (co & 3))
                     : (((co >> 2) - 4) * 8 + 4 + (co & 3));
}

// ============ K1: conv front-end, NCK chunks per block -> seq planes =======
__global__ __launch_bounds__(64) void frontend_kernel(
    const float* __restrict__ x0, const float* __restrict__ x1,
    const float* __restrict__ x2, const float* __restrict__ x3,
    const float* __restrict__ c1w, const float* __restrict__ c1b,
    const float* __restrict__ c2w, const float* __restrict__ c2b,
    unsigned short* __restrict__ seqh, unsigned short* __restrict__ seql,
    int t0, int Tseg, int nck)
{
    const int s    = blockIdx.x;
    const int br   = blockIdx.y & 3;
    const int cko  = blockIdx.y >> 2;
    const int lane = threadIdx.x;
    const float* xg = (br == 0) ? x0 : (br == 1) ? x1 : (br == 2) ? x2 : x3;

    __shared__ float xs_c[70];
    __shared__ float p1buf[34][16];

    const int ci = lane & 15;
    const int co = lane & 31;
    const int hf = lane >> 5;
    const int sp = swz(co);

    const float w10 = c1w[br * 48 + ci * 3 + 0];
    const float w11 = c1w[br * 48 + ci * 3 + 1];
    const float w12 = c1w[br * 48 + ci * 3 + 2];
    const float b1v = c1b[br * 16 + ci];

    float wt[24];
    {
        const v4f* p = (const v4f*)(c2w + br * 1536 + co * 48 + hf * 24);
        #pragma unroll
        for (int i = 0; i < 6; ++i) ((v4f*)wt)[i] = p[i];
    }
    v4f w2p[3][2];
    #pragma unroll
    for (int k = 0; k < 3; ++k)
        #pragma unroll
        for (int h2 = 0; h2 < 2; ++h2)
            w2p[k][h2] = (v4f){ wt[(h2 * 4 + 0) * 3 + k], wt[(h2 * 4 + 1) * 3 + k],
                                wt[(h2 * 4 + 2) * 3 + k], wt[(h2 * 4 + 3) * 3 + k] };
    const float b2v = c2b[br * 32 + co];

    #pragma unroll 1
    for (int ic = 0; ic < nck; ++ic) {
        const int ck  = cko * nck + ic;
        const int tc0 = t0 + ck * CH;
        const int lt0 = ck * CH;

        __syncthreads();
        {
            int g = 4 * tc0 - 3 + lane;
            xs_c[lane] = ((unsigned)g < (unsigned)LSIG) ? xg[(size_t)s * LSIG + g] : 0.f;
            if (lane < 6) {
                int g2 = 4 * tc0 + 61 + lane;
                xs_c[64 + lane] = ((unsigned)g2 < (unsigned)LSIG) ? xg[(size_t)s * LSIG + g2] : 0.f;
            }
        }
        __syncthreads();

        #pragma unroll 1
        for (int it = 0; it < 9; ++it) {
            int idx = it * 64 + lane;
            if (idx < 34 * 16) {
                int pl = idx >> 4;
                float xa = xs_c[2 * pl + 0], xb = xs_c[2 * pl + 1];
                float xc = xs_c[2 * pl + 2], xd = xs_c[2 * pl + 3];
                float a0 = fmaf(xc, w12, fmaf(xb, w11, fmaf(xa, w10, b1v)));
                float a1 = fmaf(xd, w12, fmaf(xc, w11, fmaf(xb, w10, b1v)));
                float v = fmaxf(fmaxf(a0, a1), 0.f);
                int p1g = 2 * tc0 - 1 + pl;
                v = ((unsigned)p1g < (unsigned)(LSIG / 2)) ? v : 0.f;
                p1buf[pl][idx & 15] = v;
            }
        }
        __syncthreads();

        {
            const v4f* pbase = (const v4f*)&p1buf[0][0];
            const int h2o = hf * 2;
            v4f r0a = pbase[0 * 4 + h2o], r0b = pbase[0 * 4 + h2o + 1];
            v4f r1a = pbase[1 * 4 + h2o], r1b = pbase[1 * 4 + h2o + 1];
            v4f r2a = pbase[2 * 4 + h2o], r2b = pbase[2 * 4 + h2o + 1];
            v4f r3a = pbase[3 * 4 + h2o], r3b = pbase[3 * 4 + h2o + 1];
            #pragma unroll 1
            for (int tl = 0; tl < CH; ++tl) {
                v2f aA = {0.f, 0.f}, aB = {0.f, 0.f};
                PKFMA(aA, r0a.xy, w2p[0][0].xy); PKFMA(aA, r0a.zw, w2p[0][0].zw);
                PKFMA(aA, r0b.xy, w2p[0][1].xy); PKFMA(aA, r0b.zw, w2p[0][1].zw);
                PKFMA(aA, r1a.xy, w2p[1][0].xy); PKFMA(aA, r1a.zw, w2p[1][0].zw);
                PKFMA(aA, r1b.xy, w2p[1][1].xy); PKFMA(aA, r1b.zw, w2p[1][1].zw);
                PKFMA(aA, r2a.xy, w2p[2][0].xy); PKFMA(aA, r2a.zw, w2p[2][0].zw);
                PKFMA(aA, r2b.xy, w2p[2][1].xy); PKFMA(aA, r2b.zw, w2p[2][1].zw);
                PKFMA(aB, r1a.xy, w2p[0][0].xy); PKFMA(aB, r1a.zw, w2p[0][0].zw);
                PKFMA(aB, r1b.xy, w2p[0][1].xy); PKFMA(aB, r1b.zw, w2p[0][1].zw);
                PKFMA(aB, r2a.xy, w2p[1][0].xy); PKFMA(aB, r2a.zw, w2p[1][0].zw);
                PKFMA(aB, r2b.xy, w2p[1][1].xy); PKFMA(aB, r2b.zw, w2p[1][1].zw);
                PKFMA(aB, r3a.xy, w2p[2][0].xy); PKFMA(aB, r3a.zw, w2p[2][0].zw);
                PKFMA(aB, r3b.xy, w2p[2][1].xy); PKFMA(aB, r3b.zw, w2p[2][1].zw);
                float sA = aA.x + aA.y, sB = aB.x + aB.y;
                sA += __shfl_xor(sA, 32);
                sB += __shfl_xor(sB, 32);
                float sv = fmaxf(fmaxf(sA, sB) + b2v, 0.f);
                unsigned short hb = bf16rne(sv);
                float hif = __uint_as_float(((unsigned)hb) << 16);
                unsigned short lb = bf16rne(sv - hif);
                size_t off = (((size_t)br * Tseg + (lt0 + tl)) * 2048 + s) * 32 + sp;
                if (hf == 0) seqh[off] = hb;
                else         seql[off] = lb;
                r0a = r2a; r0b = r2b; r1a = r3a; r1b = r3b;
                if (tl < CH - 1) {
                    r2a = pbase[(2 * tl + 4) * 4 + h2o]; r2b = pbase[(2 * tl + 4) * 4 + h2o + 1];
                    r3a = pbase[(2 * tl + 5) * 4 + h2o]; r3b = pbase[(2 * tl + 5) * 4 + h2o + 1];
                }
            }
        }
    }
}

// ============ K2: MFMA LSTM, 16 samples/wave — copy-free prefetch ==========
// R18: the per-step register copy of in-flight loads (nh1=nh2) forced
// s_waitcnt vmcnt(0) ~200cyc after issue => synchronous HBM wait every step
// (the stubborn ~4500cyc/step). Fix: 2x-unrolled loop with ALTERNATING
// prefetch registers; loads issued one full step before first use; no copies.
__global__ __launch_bounds__(64, 1) void lstm_mfma_kernel(
    const unsigned short* __restrict__ seqh, const unsigned short* __restrict__ seql,
    const float* __restrict__ wih, const float* __restrict__ whh,
    const float* __restrict__ bih, const float* __restrict__ bhh,
    float* __restrict__ state, float* __restrict__ feats,
    int t0, int Tseg)
{
    const int s0   = blockIdx.x * 16;
    const int br   = blockIdx.y;
    const int lane = threadIdx.x;
    const int c    = lane & 15;   // sample col
    const int q    = lane >> 4;

    __shared__ f32x4 bias_lds[8][64];
    #pragma unroll
    for (int n = 0; n < 8; ++n) {
        f32x4 b;
        #pragma unroll
        for (int r = 0; r < 4; ++r) {
            int g = 16 * n + 4 * q + r;
            b[r] = bih[br * 128 + g] + bhh[br * 128 + g];
        }
        bias_lds[n][lane] = b;
    }
    __syncthreads();

    // weight A-frags: row = c (gate 16n+c), k elems {4q+j} u {16+4q+j}
    b16x8 wihhi[8], wihlo[8], whhhi[8], whhlo[8];
    #pragma unroll
    for (int n = 0; n < 8; ++n) {
        const int gr = 16 * n + c;
        const float* pi = wih + (size_t)br * 4096 + (size_t)gr * 32;
        const float* phw = whh + (size_t)br * 4096 + (size_t)gr * 32;
        v4f ia = *(const v4f*)(pi + 4 * q);
        v4f ib = *(const v4f*)(pi + 16 + 4 * q);
        v4f ha = *(const v4f*)(phw + 4 * q);
        v4f hb = *(const v4f*)(phw + 16 + 4 * q);
        #pragma unroll
        for (int j = 0; j < 4; ++j) {
            __bf16 t;
            t = (__bf16)ia[j]; wihhi[n][j]     = t; wihlo[n][j]     = (__bf16)(ia[j] - (float)t);
            t = (__bf16)ib[j]; wihhi[n][4 + j] = t; wihlo[n][4 + j] = (__bf16)(ib[j] - (float)t);
            t = (__bf16)ha[j]; whhhi[n][j]     = t; whhlo[n][j]     = (__bf16)(ha[j] - (float)t);
            t = (__bf16)hb[j]; whhhi[n][4 + j] = t; whhlo[n][4 + j] = (__bf16)(hb[j] - (float)t);
        }
    }

    // state: init or restore
    b16x8 bhh_f, bhl_f;
    float cst[2][4];
    if (t0 == 0) {
        #pragma unroll
        for (int j = 0; j < 8; ++j) { bhh_f[j] = (__bf16)0.f; bhl_f[j] = (__bf16)0.f; }
        #pragma unroll
        for (int hh = 0; hh < 2; ++hh)
            #pragma unroll
            for (int r = 0; r < 4; ++r) cst[hh][r] = 0.f;
    } else {
        const float* st = state + (((size_t)br * BATCH + s0 + c) * 2) * 32;
        #pragma unroll
        for (int hh = 0; hh < 2; ++hh)
            #pragma unroll
            for (int r = 0; r < 4; ++r) {
                int u = 16 * hh + 4 * q + r;
                float hv = st[u];
                __bf16 hb2 = (__bf16)hv;
                bhh_f[hh * 4 + r] = hb2;
                bhl_f[hh * 4 + r] = (__bf16)(hv - (float)hb2);
                cst[hh][r] = st[32 + u];
            }
    }

    // x pointers
    const size_t xbase = ((size_t)br * Tseg * 2048 + s0 + c) * 32 + (size_t)q * 8;
    const size_t xstep = 2048 * 32;
    const unsigned short* ph = seqh + xbase;
    const unsigned short* pl = seql + xbase;

    // prologue: xacc = bias + Wih*x(0); nh1 = x(1)
    f32x4 xacc[8];
    b16x8 nh1, nl1;
    {
        b16x8 x0h = *(const b16x8*)ph;
        b16x8 x0l = *(const b16x8*)pl;
        #pragma unroll
        for (int n = 0; n < 8; ++n) {
            xacc[n] = __builtin_amdgcn_mfma_f32_16x16x32_bf16(wihhi[n], x0h, bias_lds[n][lane], 0, 0, 0);
            xacc[n] = __builtin_amdgcn_mfma_f32_16x16x32_bf16(wihhi[n], x0l, xacc[n], 0, 0, 0);
            xacc[n] = __builtin_amdgcn_mfma_f32_16x16x32_bf16(wihlo[n], x0h, xacc[n], 0, 0, 0);
        }
        nh1 = *(const b16x8*)(ph + xstep);
        nl1 = *(const b16x8*)(pl + xstep);
    }

    // one LSTM step body: h-MFMAs on xacc, activations, repack, opt. store
#define STEP_BODY(LAST)                                                          \
    {                                                                            \
        _Pragma("unroll")                                                        \
        for (int n = 0; n < 8; ++n) {                                            \
            xacc[n] = __builtin_amdgcn_mfma_f32_16x16x32_bf16(whhhi[n], bhh_f, xacc[n], 0, 0, 0); \
            xacc[n] = __builtin_amdgcn_mfma_f32_16x16x32_bf16(whhhi[n], bhl_f, xacc[n], 0, 0, 0); \
            xacc[n] = __builtin_amdgcn_mfma_f32_16x16x32_bf16(whhlo[n], bhh_f, xacc[n], 0, 0, 0); \
        }                                                                        \
        float hv[8];                                                             \
        _Pragma("unroll")                                                        \
        for (int hh = 0; hh < 2; ++hh) {                                         \
            _Pragma("unroll")                                                    \
            for (int r = 0; r < 4; ++r) {                                        \
                float gi = xacc[0 + hh][r];                                      \
                float gf = xacc[2 + hh][r];                                      \
                float gg = xacc[4 + hh][r];                                      \
                float go = xacc[6 + hh][r];                                      \
                float si = sigf(gi);                                             \
                float sf = sigf(gf);                                             \
                float tg = tanhfast(gg);                                         \
                float so = sigf(go);                                             \
                float cc = fmaf(sf, cst[hh][r], si * tg);                        \
                cst[hh][r] = cc;                                                 \
                hv[hh * 4 + r] = so * tanhfast(cc);                              \
            }                                                                    \
        }                                                                        \
        u32x4 hd_, ld_;                                                          \
        _Pragma("unroll")                                                        \
        for (int p = 0; p < 4; ++p) {                                            \
            float a = hv[2 * p], b = hv[2 * p + 1];                              \
            unsigned d = cvtpk_bf16(a, b);                                       \
            float fa = __uint_as_float(d << 16);                                 \
            float fb = __uint_as_float(d & 0xFFFF0000u);                         \
            ld_[p] = cvtpk_bf16(a - fa, b - fb);                                 \
            hd_[p] = d;                                                          \
        }                                                                        \
        bhh_f = __builtin_bit_cast(b16x8, hd_);                                  \
        bhl_f = __builtin_bit_cast(b16x8, ld_);                                  \
        if (LAST) {                                                              \
            float* fp = feats + ((size_t)br * BATCH + s0 + c) * 32 + 4 * q;      \
            _Pragma("unroll")                                                    \
            for (int r = 0; r < 4; ++r) { fp[r] = hv[r]; fp[16 + r] = hv[4 + r]; } \
        }                                                                        \
    }

#define XACC_FROM(XH, XL)                                                        \
    {                                                                            \
        _Pragma("unroll")                                                        \
        for (int n = 0; n < 8; ++n) {                                            \
            xacc[n] = __builtin_amdgcn_mfma_f32_16x16x32_bf16(wihhi[n], XH, bias_lds[n][lane], 0, 0, 0); \
            xacc[n] = __builtin_amdgcn_mfma_f32_16x16x32_bf16(wihhi[n], XL, xacc[n], 0, 0, 0); \
            xacc[n] = __builtin_amdgcn_mfma_f32_16x16x32_bf16(wihlo[n], XH, xacc[n], 0, 0, 0); \
        }                                                                        \
    }

    #pragma unroll 1
    for (int t = 0; t < Tseg; t += 2) {
        // ===== even step t (never the global last: TSTEPS-1 is odd) =====
        b16x8 pbh, pbl;                    // prefetch x(t+2)
        if (t + 2 < Tseg) {
            pbh = *(const b16x8*)(ph + (size_t)(t + 2) * xstep);
            pbl = *(const b16x8*)(pl + (size_t)(t + 2) * xstep);
        }
        STEP_BODY(false)
        XACC_FROM(nh1, nl1)                // consumes x(t+1), issued >=1 step ago

        // ===== odd step t+1 =====
        const bool last = (t0 + t + 1 == TSTEPS - 1);
        if (t + 3 < Tseg) {                // prefetch x(t+3) into nh1 (just consumed)
            nh1 = *(const b16x8*)(ph + (size_t)(t + 3) * xstep);
            nl1 = *(const b16x8*)(pl + (size_t)(t + 3) * xstep);
        }
        STEP_BODY(last)
        if (t + 2 < Tseg) { XACC_FROM(pbh, pbl) }   // consumes x(t+2)
    }
#undef STEP_BODY
#undef XACC_FROM

    // save state for next segment
    if (t0 + Tseg < TSTEPS) {
        float* st = state + (((size_t)br * BATCH + s0 + c) * 2) * 32;
        #pragma unroll
        for (int hh = 0; hh < 2; ++hh)
            #pragma unroll
            for (int r = 0; r < 4; ++r) {
                int u = 16 * hh + 4 * q + r;
                st[u]      = (float)bhh_f[hh * 4 + r] + (float)bhl_f[hh * 4 + r];
                st[32 + u] = cst[hh][r];
            }
    }
}

// ============ fallback: R7 monolithic branch kernel ========================
__global__ __launch_bounds__(64, 2) void branch_fallback(
    const float* __restrict__ x0, const float* __restrict__ x1,
    const float* __restrict__ x2, const float* __restrict__ x3,
    const float* __restrict__ c1w, const float* __restrict__ c1b,
    const float* __restrict__ c2w, const float* __restrict__ c2b,
    const float* __restrict__ wih, const float* __restrict__ whh,
    const float* __restrict__ bih, const float* __restrict__ bhh,
    float* __restrict__ feats)
{
    const int s    = blockIdx.x;
    const int br   = blockIdx.y;
    const int lane = threadIdx.x;
    const float* xg = (br == 0) ? x0 : (br == 1) ? x1 : (br == 2) ? x2 : x3;

    __shared__ float xs_c[70];
    __shared__ float p1buf[34][16];
    __shared__ float seqb[CH][32];
    __shared__ float hb[2][32];

    const int ci = lane & 15;
    const int co = lane & 31;
    const int hf = lane >> 5;

    const float bs0 = bih[br * 128 + lane]      + bhh[br * 128 + lane];
    const float bs1 = bih[br * 128 + lane + 64] + bhh[br * 128 + lane + 64];

    if (lane < 32) hb[0][lane] = 0.f;
    float c_state = 0.f;

    #pragma unroll 1
    for (int chk = 0; chk < NCHUNK; ++chk) {
        const int tc0 = chk * CH;
        {
            int g = 4 * tc0 - 3 + lane;
            xs_c[lane] = ((unsigned)g < (unsigned)LSIG) ? xg[(size_t)s * LSIG + g] : 0.f;
            if (lane < 6) {
                int g2 = 4 * tc0 + 61 + lane;
                xs_c[64 + lane] = ((unsigned)g2 < (unsigned)LSIG) ? xg[(size_t)s * LSIG + g2] : 0.f;
            }
        }
        const float* pc1 = c1w + br * 48 + ci * 3;  asm volatile("" : "+v"(pc1));
        const float w10 = pc1[0], w11 = pc1[1], w12 = pc1[2];
        const float* pb1 = c1b + br * 16 + ci;      asm volatile("" : "+v"(pb1));
        const float b1v = pb1[0];
        const float* pc2 = c2w + br * 1536 + co * 48 + hf * 24;
        asm volatile("" : "+v"(pc2));
        float wt[24];
        #pragma unroll
        for (int i = 0; i < 6; ++i) ((v4f*)wt)[i] = ((const v4f*)pc2)[i];
        v4f w2p[3][2];
        #pragma unroll
        for (int k = 0; k < 3; ++k)
            #pragma unroll
            for (int h2 = 0; h2 < 2; ++h2)
                w2p[k][h2] = (v4f){ wt[(h2 * 4 + 0) * 3 + k], wt[(h2 * 4 + 1) * 3 + k],
                                    wt[(h2 * 4 + 2) * 3 + k], wt[(h2 * 4 + 3) * 3 + k] };
        const float* pb2 = c2b + br * 32 + co;      asm volatile("" : "+v"(pb2));
        const float b2v = pb2[0];
        __syncthreads();
        #pragma unroll 1
        for (int it = 0; it < 9; ++it) {
            int idx = it * 64 + lane;
            if (idx < 34 * 16) {
                int pl = idx >> 4;
                float xa = xs_c[2 * pl + 0], xb = xs_c[2 * pl + 1];
                float xc = xs_c[2 * pl + 2], xd = xs_c[2 * pl + 3];
                float a0 = fmaf(xc, w12, fmaf(xb, w11, fmaf(xa, w10, b1v)));
                float a1 = fmaf(xd, w12, fmaf(xc, w11, fmaf(xb, w10, b1v)));
                float v = fmaxf(fmaxf(a0, a1), 0.f);
                int p1g = 2 * tc0 - 1 + pl;
                v = ((unsigned)p1g < (unsigned)(LSIG / 2)) ? v : 0.f;
                p1buf[pl][idx & 15] = v;
            }
        }
        __syncthreads();
        {
            const v4f* pbase = (const v4f*)&p1buf[0][0];
            const int h2o = hf * 2;
            v4f r0a = pbase[0 * 4 + h2o], r0b = pbase[0 * 4 + h2o + 1];
            v4f r1a = pbase[1 * 4 + h2o], r1b = pbase[1 * 4 + h2o + 1];
            v4f r2a = pbase[2 * 4 + h2o], r2b = pbase[2 * 4 + h2o + 1];
            v4f r3a = pbase[3 * 4 + h2o], r3b = pbase[3 * 4 + h2o + 1];
            #pragma unroll 1
            for (int tl = 0; tl < CH; ++tl) {
                v2f aA = {0.f, 0.f}, aB = {0.f, 0.f};
                PKFMA(aA, r0a.xy, w2p[0][0].xy); PKFMA(aA, r0a.zw, w2p[0][0].zw);
                PKFMA(aA, r0b.xy, w2p[0][1].xy); PKFMA(aA, r0b.zw, w2p[0][1].zw);
                PKFMA(aA, r1a.xy, w2p[1][0].xy); PKFMA(aA, r1a.zw, w2p[1][0].zw);
                PKFMA(aA, r1b.xy, w2p[1][1].xy); PKFMA(aA, r1b.zw, w2p[1][1].zw);
                PKFMA(aA, r2a.xy, w2p[2][0].xy); PKFMA(aA, r2a.zw, w2p[2][0].zw);
                PKFMA(aA, r2b.xy, w2p[2][1].xy); PKFMA(aA, r2b.zw, w2p[2][1].zw);
                PKFMA(aB, r1a.xy, w2p[0][0].xy); PKFMA(aB, r1a.zw, w2p[0][0].zw);
                PKFMA(aB, r1b.xy, w2p[0][1].xy); PKFMA(aB, r1b.zw, w2p[0][1].zw);
                PKFMA(aB, r2a.xy, w2p[1][0].xy); PKFMA(aB, r2a.zw, w2p[1][0].zw);
                PKFMA(aB, r2b.xy, w2p[1][1].xy); PKFMA(aB, r2b.zw, w2p[1][1].zw);
                PKFMA(aB, r3a.xy, w2p[2][0].xy); PKFMA(aB, r3a.zw, w2p[2][0].zw);
                PKFMA(aB, r3b.xy, w2p[2][1].xy); PKFMA(aB, r3b.zw, w2p[2][1].zw);
                float sA = aA.x + aA.y, sB = aB.x + aB.y;
                sA += __shfl_xor(sA, 32);
                sB += __shfl_xor(sB, 32);
                if (hf == 0)
                    seqb[tl][co] = fmaxf(fmaxf(sA, sB) + b2v, 0.f);
                r0a = r2a; r0b = r2b; r1a = r3a; r1b = r3b;
                if (tl < CH - 1) {
                    r2a = pbase[(2 * tl + 4) * 4 + h2o]; r2b = pbase[(2 * tl + 4) * 4 + h2o + 1];
                    r3a = pbase[(2 * tl + 5) * 4 + h2o]; r3b = pbase[(2 * tl + 5) * 4 + h2o + 1];
                }
            }
        }
        __syncthreads();
        float gpx0[CH], gpx1[CH];
        {
            const float* pwi = wih + (size_t)br * 4096 + (size_t)lane * 32;
            asm volatile("" : "+v"(pwi));
            v4f wiA[8], wiB[8];
            #pragma unroll
            for (int j = 0; j < 8; ++j) {
                wiA[j] = ((const v4f*)pwi)[j];
                wiB[j] = ((const v4f*)(pwi + 64 * 32))[j];
            }
            #pragma unroll
            for (int tl = 0; tl < CH; ++tl) {
                const v4f* xq = (const v4f*)&seqb[tl][0];
                v2f aA = {0.f, 0.f}, aB = {0.f, 0.f};
                #pragma unroll
                for (int j = 0; j < 8; ++j) {
                    v4f xv = xq[j];
                    PKFMA(aA, xv.xy, wiA[j].xy); PKFMA(aA, xv.zw, wiA[j].zw);
                    PKFMA(aB, xv.xy, wiB[j].xy); PKFMA(aB, xv.zw, wiB[j].zw);
                }
                gpx0[tl] = aA.x + aA.y;
                gpx1[tl] = aB.x + aB.y;
            }
        }
        {
            const float* pwh = whh + (size_t)br * 4096 + (size_t)lane * 32;
            asm volatile("" : "+v"(pwh));
            v4f whA[8], whB[8];
            #pragma unroll
            for (int j = 0; j < 8; ++j) {
                whA[j] = ((const v4f*)pwh)[j];
                whB[j] = ((const v4f*)(pwh + 64 * 32))[j];
            }
            #pragma unroll
            for (int tl = 0; tl < CH; ++tl) {
                __syncthreads();
                const int p = (tc0 + tl) & 1;
                const v4f* hq = (const v4f*)&hb[p][0];
                v2f aA = {0.f, 0.f}, aB = {0.f, 0.f};
                #pragma unroll
                for (int j = 0; j < 8; ++j) {
                    v4f hv = hq[j];
                    PKFMA(aA, hv.xy, whA[j].xy); PKFMA(aA, hv.zw, whA[j].zw);
                    PKFMA(aB, hv.xy, whB[j].xy); PKFMA(aB, hv.zw, whB[j].zw);
                }
                float g0 = bs0 + gpx0[tl] + aA.x + aA.y;
                float g1 = bs1 + gpx1[tl] + aB.x + aB.y;
                float a0 = sigf(g0);
                float earg = (lane < 32) ? 2.f * g1 : -g1;
                float e1 = __expf(fminf(earg, 80.f));
                float num = (lane < 32) ? e1 - 1.f : 1.f;
                float a1 = __fdividef(num, e1 + 1.f);
                float fa = __shfl_xor(a0, 32);
                float oa = __shfl_xor(a1, 32);
                if (lane < 32) {
                    c_state = fmaf(fa, c_state, a0 * a1);
                    hb[p ^ 1][lane] = oa * tanhfast(c_state);
                }
            }
        }
    }
    __syncthreads();
    if (lane < 32)
        feats[((size_t)br * BATCH + s) * 32 + lane] = hb[0][lane];
}

// ---------------- tail: bottleneck + 8-qubit statevector + classifier -------

__device__ __forceinline__ void apply1q(float2* psi, int lane, int q,
                                        float2 g00, float2 g01,
                                        float2 g10, float2 g11)
{
    const int shift = 7 - q;
    const int right = 1 << shift;
    #pragma unroll
    for (int pp = 0; pp < 2; ++pp) {
        int p  = lane + 64 * pp;
        int l  = p >> shift;
        int r  = p & (right - 1);
        int i0 = (l << (shift + 1)) + r;
        int i1 = i0 + right;
        float2 a = psi[i0], b = psi[i1];
        float2 n0 = make_float2(g00.x * a.x - g00.y * a.y + g01.x * b.x - g01.y * b.y,
                                g00.x * a.y + g00.y * a.x + g01.x * b.y + g01.y * b.x);
        float2 n1 = make_float2(g10.x * a.x - g10.y * a.y + g11.x * b.x - g11.y * b.y,
                                g10.x * a.y + g10.y * a.x + g11.x * b.y + g11.y * b.x);
        psi[i0] = n0;
        psi[i1] = n1;
    }
    __syncthreads();
}

__global__ __launch_bounds__(64) void tail_kernel(
    const float* __restrict__ feats, const float* __restrict__ bw,
    const float* __restrict__ bb, const float* __restrict__ qw,
    const float* __restrict__ cw, const float* __restrict__ cb,
    float* __restrict__ out)
{
    const int s    = blockIdx.x;
    const int lane = threadIdx.x;

    __shared__ float comb[128];
    __shared__ float2 psi[256];
    __shared__ float ang[8];

    comb[lane]      = feats[(size_t)(lane >> 5) * (BATCH * 32) + (size_t)s * 32 + (lane & 31)];
    comb[lane + 64] = feats[(size_t)((lane + 64) >> 5) * (BATCH * 32) + (size_t)s * 32 + (lane & 31)];
    __syncthreads();

    {
        int q = lane >> 3, k0 = lane & 7;
        float p = 0.f;
        #pragma unroll
        for (int i = 0; i < 16; ++i) {
            int k = k0 + 8 * i;
            p = fmaf(comb[k], bw[q * 128 + k], p);
        }
        p += __shfl_xor(p, 4);
        p += __shfl_xor(p, 2);
        p += __shfl_xor(p, 1);
        if (k0 == 0) ang[q] = tanhf(p + bb[q]);
    }
    #pragma unroll
    for (int r = 0; r < 4; ++r) {
        int idx = lane + 64 * r;
        psi[idx] = make_float2(idx == 0 ? 1.f : 0.f, 0.f);
    }
    __syncthreads();

    const float PI_F = 3.14159265358979323846f;

    for (int q = 0; q < 8; ++q) {
        float half = ang[q] * PI_F * 0.5f;
        float cv = cosf(half), sv = sinf(half);
        apply1q(psi, lane, q,
                make_float2(cv, 0.f), make_float2(0.f, -sv),
                make_float2(0.f, -sv), make_float2(cv, 0.f));
    }

    for (int l = 0; l < 3; ++l) {
        for (int q = 0; q < 8; ++q) {
            float phi = qw[(l * 8 + q) * 3 + 0];
            float th  = qw[(l * 8 + q) * 3 + 1];
            float om  = qw[(l * 8 + q) * 3 + 2];
            float ct = cosf(0.5f * th), st = sinf(0.5f * th);
            float A = 0.5f * (phi + om), D = 0.5f * (phi - om);
            float cA = cosf(A), sA = sinf(A), cD = cosf(D), sD = sinf(D);
            apply1q(psi, lane, q,
                    make_float2(ct * cA, -ct * sA), make_float2(-st * cD, -st * sD),
                    make_float2(st * cD, -st * sD), make_float2(ct * cA,  ct * sA));
        }
        int stride = l + 1;
        for (int q = 0; q + stride < 8; ++q) {
            int cbit = 1 << (7 - q);
            int tbit = 1 << (7 - (q + stride));
            #pragma unroll
            for (int r = 0; r < 4; ++r) {
                int idx = lane + 64 * r;
                if ((idx & cbit) && !(idx & tbit)) {
                    int j = idx | tbit;
                    float2 tmp = psi[idx];
                    psi[idx] = psi[j];
                    psi[j] = tmp;
                }
            }
            __syncthreads();
        }
    }

    float z[8];
    #pragma unroll
    for (int q = 0; q < 8; ++q) z[q] = 0.f;
    #pragma unroll
    for (int r = 0; r < 4; ++r) {
        int idx = lane + 64 * r;
        float2 a = psi[idx];
        float pr = a.x * a.x + a.y * a.y;
        #pragma unroll
        for (int q = 0; q < 8; ++q)
            z[q] += (idx & (1 << (7 - q))) ? -pr : pr;
    }
    #pragma unroll
    for (int q = 0; q < 8; ++q) {
        #pragma unroll
        for (int off = 32; off; off >>= 1) z[q] += __shfl_xor(z[q], off);
    }
    if (lane == 0) {
        #pragma unroll
        for (int c = 0; c < 3; ++c) {
            float acc = cb[c];
            #pragma unroll
            for (int q = 0; q < 8; ++q) acc = fmaf(z[q], cw[c * 8 + q], acc);
            out[s * 3 + c] = acc;
        }
    }
}

extern "C" void kernel_launch(void* const* d_in, const int* in_sizes, int n_in,
                              void* d_out, int out_size, void* d_ws, size_t ws_size,
                              hipStream_t stream)
{
    (void)in_sizes; (void)n_in; (void)out_size;
    const float* x0  = (const float*)d_in[0];
    const float* x1  = (const float*)d_in[1];
    const float* x2  = (const float*)d_in[2];
    const float* x3  = (const float*)d_in[3];
    const float* c1w = (const float*)d_in[4];
    const float* c1b = (const float*)d_in[5];
    const float* c2w = (const float*)d_in[6];
    const float* c2b = (const float*)d_in[7];
    const float* wih = (const float*)d_in[8];
    const float* whh = (const float*)d_in[9];
    const float* bih = (const float*)d_in[10];
    const float* bhh = (const float*)d_in[11];
    const float* bw  = (const float*)d_in[12];
    const float* bb  = (const float*)d_in[13];
    const float* qw  = (const float*)d_in[14];
    const float* cw  = (const float*)d_in[15];
    const float* cb  = (const float*)d_in[16];

    const size_t state_b = 4ULL * BATCH * 64ULL * 4ULL;       // 2 MB
    const size_t feats_b = 4ULL * BATCH * 32ULL * 4ULL;       // 1 MB
    const size_t per_t   = 4ULL * 2048ULL * 32ULL * 4ULL;     // 1 MB/step (hi+lo)

    int Tseg = 0;
    for (int cand = 512; cand >= 32; cand >>= 1) {
        if ((size_t)cand * per_t + state_b + feats_b <= ws_size) { Tseg = cand; break; }
    }

    if (Tseg > 0) {
        size_t seg_elems = (size_t)Tseg * 4ULL * 2048ULL * 32ULL;
        unsigned short* seqh = (unsigned short*)d_ws;
        unsigned short* seql = seqh + seg_elems;
        float* state = (float*)((char*)d_ws + 2ULL * seg_elems * 2ULL);
        float* feats = (float*)((char*)state + state_b);

        const int slots = Tseg / CH;
        const int nck   = (slots >= 4) ? 4 : slots;

        for (int t0 = 0; t0 < TSTEPS; t0 += Tseg) {
            frontend_kernel<<<dim3(BATCH, 4 * (slots / nck)), 64, 0, stream>>>(
                x0, x1, x2, x3, c1w, c1b, c2w, c2b, seqh, seql, t0, Tseg, nck);
            lstm_mfma_kernel<<<dim3(BATCH / 16, 4), 64, 0, stream>>>(
                seqh, seql, wih, whh, bih, bhh, state, feats, t0, Tseg);
        }
        tail_kernel<<<BATCH, 64, 0, stream>>>(
            feats, bw, bb, qw, cw, cb, (float*)d_out);
    } else {
        float* feats = (float*)d_ws;
        branch_fallback<<<dim3(BATCH, 4), 64, 0, stream>>>(
            x0, x1, x2, x3, c1w, c1b, c2w, c2b, wih, whh, bih, bhh, feats);
        tail_kernel<<<BATCH, 64, 0, stream>>>(
            feats, bw, bb, qw, cw, cb, (float*)d_out);
    }
}